// Round 21
// baseline (429.639 us; speedup 1.0000x reference)
//
#include <hip/hip_runtime.h>
#include <hip/hip_bf16.h>

typedef __attribute__((ext_vector_type(8))) short short8;
typedef __attribute__((ext_vector_type(4))) float f32x4;
typedef __attribute__((ext_vector_type(4))) unsigned int u32x4;

#define T_STEPS 48
#define BATCH 32
#define EDIM 512
#define HDIM 1024
#define VOCAB 32000
#define GRU_BLOCKS 64
#define JPB 16
#define SENT 0x7FFF7FFFu
#define N_BIG 625                  // stripes 0..4: 256x256 tiles (5 x 125)
#define N_TILES 875                // + stripe 5 as 250 tiles of 128x256
#define CNT_STRIDE 16              // uints per t-slot (64B padded)
#define EARLY_WORKERS 96           // blocks 64..159 work during gru; 160+ throttled

// packed h storage (hi-plane only): uint words, [t(49)][k_pair(512)][b(32)]
#define HS_T_STRIDE 16384          // uints per t-slot

__device__ __forceinline__ unsigned short f2bf(float f) {
    __hip_bfloat16 h = __float2bfloat16(f);
    return *reinterpret_cast<unsigned short*>(&h);
}
__device__ __forceinline__ float bf2f(unsigned short u) {
    union { unsigned int i; float f; } v;
    v.i = ((unsigned int)u) << 16;
    return v.f;
}

typedef __attribute__((address_space(1))) const void GAS;
typedef __attribute__((address_space(3))) void LAS;
__device__ __forceinline__ void gload_lds16(const unsigned short* g, unsigned short* l) {
    __builtin_amdgcn_global_load_lds((GAS*)g, (LAS*)(unsigned)(uintptr_t)l, 16, 0, 0);
}

// coherent (cross-XCD visible) 16B store
__device__ __forceinline__ void store16_coh(unsigned int* p, u32x4 v) {
    asm volatile("global_store_dwordx4 %0, %1, off sc0 sc1"
                 :: "v"((unsigned long long)(uintptr_t)p), "v"(v) : "memory");
}

// ---------------- prep: conversions, gather, h0 pack, sentinel fill, cnt/queue zero ----------------
__global__ __launch_bounds__(256) void prep_kernel(
    const float* __restrict__ h0, const int* __restrict__ tseq,
    const float* __restrict__ emb, const float* __restrict__ w_ih,
    const float* __restrict__ w_hh, const float* __restrict__ w_cls,
    unsigned short* __restrict__ wcls_bf, unsigned short* __restrict__ wih_bf,
    unsigned short* __restrict__ whh_bf, unsigned short* __restrict__ x_bf,
    unsigned int* __restrict__ hs32, unsigned int* __restrict__ cnt8)
{
    const long R0 = (long)VOCAB * HDIM / 4;           // w_cls
    const long R1 = (long)3 * HDIM * EDIM / 4;        // w_ih
    const long R2 = (long)3 * HDIM * HDIM / 4;        // w_hh (hi only)
    const long R3 = (long)T_STEPS * BATCH * EDIM / 4; // X gather
    const long R4 = (long)HS_T_STRIDE;                // h0 -> packed slot 0
    const long R5 = (long)T_STEPS * HS_T_STRIDE / 4;  // sentinel fill t=1..48 (uint4)
    const long R6 = 512;                              // cnt8(padded)+tileq zero: 2048 uints
    const long total = R0 + R1 + R2 + R3 + R4 + R5 + R6;

    for (long i = (long)blockIdx.x * blockDim.x + threadIdx.x; i < total;
         i += (long)gridDim.x * blockDim.x) {
        if (i < R0) {
            float4 v = reinterpret_cast<const float4*>(w_cls)[i];
            ushort4 u = { f2bf(v.x), f2bf(v.y), f2bf(v.z), f2bf(v.w) };
            *reinterpret_cast<ushort4*>(wcls_bf + i * 4) = u;
        } else if (i < R0 + R1) {
            long j = i - R0;
            float4 v = reinterpret_cast<const float4*>(w_ih)[j];
            ushort4 u = { f2bf(v.x), f2bf(v.y), f2bf(v.z), f2bf(v.w) };
            *reinterpret_cast<ushort4*>(wih_bf + j * 4) = u;
        } else if (i < R0 + R1 + R2) {
            long j = i - R0 - R1;
            float4 v = reinterpret_cast<const float4*>(w_hh)[j];
            ushort4 u = { f2bf(v.x), f2bf(v.y), f2bf(v.z), f2bf(v.w) };
            *reinterpret_cast<ushort4*>(whh_bf + j * 4) = u;
        } else if (i < R0 + R1 + R2 + R3) {
            long j = i - R0 - R1 - R2;
            int m = (int)(j >> 7);
            int kk4 = (int)(j & 127);
            int t = m >> 5, b = m & 31;
            int tok = tseq[b * T_STEPS + t];
            float4 v = reinterpret_cast<const float4*>(emb)[(long)tok * (EDIM / 4) + kk4];
            ushort4 u = { f2bf(v.x), f2bf(v.y), f2bf(v.z), f2bf(v.w) };
            *reinterpret_cast<ushort4*>(x_bf + (long)m * EDIM + kk4 * 4) = u;
        } else if (i < R0 + R1 + R2 + R3 + R4) {
            long j = i - R0 - R1 - R2 - R3;       // uint index: w*32 + b
            int w = (int)(j >> 5), b = (int)(j & 31);
            unsigned short a = f2bf(h0[b * HDIM + 2 * w]);
            unsigned short c = f2bf(h0[b * HDIM + 2 * w + 1]);
            hs32[j] = (unsigned)a | ((unsigned)c << 16);
        } else if (i < R0 + R1 + R2 + R3 + R4 + R5) {
            long j = i - R0 - R1 - R2 - R3 - R4;
            uint4 s = { SENT, SENT, SENT, SENT };
            reinterpret_cast<uint4*>(hs32 + HS_T_STRIDE)[j] = s;   // t=1..48
        } else {
            long j = i - R0 - R1 - R2 - R3 - R4 - R5;
            uint4 z = { 0u, 0u, 0u, 0u };
            reinterpret_cast<uint4*>(cnt8)[j] = z;
        }
    }
}

// ---------------- GI GEMM: gi = X @ W_ih^T + b_ih (proven gload_lds 128x128) ----------------
__global__ __launch_bounds__(256) void gemm_gi(
    const unsigned short* __restrict__ A, const unsigned short* __restrict__ B,
    const float* __restrict__ bias, float* __restrict__ C, int K, int Ntot, int nM)
{
    const int nwg = gridDim.x;
    const int lin = blockIdx.x;
    const int q = nwg >> 3;
    const int wg = (lin & 7) * q + (lin >> 3);
    const int mi = wg % nM, ni = wg / nM;
    const int m0 = mi * 128, n0 = ni * 128;

    const int tid = threadIdx.x;
    const int lane = tid & 63;
    const int wid = tid >> 6;
    const int wr = wid >> 1, wc = wid & 1;

    __shared__ __align__(16) unsigned short As[128 * 32];
    __shared__ __align__(16) unsigned short Bs[128 * 32];

    f32x4 acc[4][4] = {};
    const int NT = K >> 5;
    const int srow = (lane >> 2);
    const int skk = (lane & 3) * 8;

    for (int kt = 0; kt < NT; ++kt) {
        __syncthreads();
        {
            const int kb = kt * 32;
#pragma unroll
            for (int h2 = 0; h2 < 2; ++h2) {
                const int i = wid + h2 * 4;
                const int row = i * 16 + srow;
                gload_lds16(A + (size_t)(m0 + row) * K + kb + skk, As + i * 512);
                gload_lds16(B + (size_t)(n0 + row) * K + kb + skk, Bs + i * 512);
            }
        }
        __syncthreads();

        const int kg = lane >> 4;
        const int l15 = lane & 15;
        short8 af[4], bf[4];
#pragma unroll
        for (int i = 0; i < 4; ++i) {
            af[i] = *(const short8*)(As + ((wr * 64 + i * 16 + l15) * 32 + kg * 8));
            bf[i] = *(const short8*)(Bs + ((wc * 64 + i * 16 + l15) * 32 + kg * 8));
        }
#pragma unroll
        for (int i = 0; i < 4; ++i)
#pragma unroll
            for (int j = 0; j < 4; ++j)
                acc[i][j] = __builtin_amdgcn_mfma_f32_16x16x32_bf16(af[i], bf[j], acc[i][j], 0, 0, 0);
    }

    const int l15 = lane & 15, lhi = lane >> 4;
#pragma unroll
    for (int i = 0; i < 4; ++i)
#pragma unroll
        for (int j = 0; j < 4; ++j) {
            int col = n0 + wc * 64 + j * 16 + l15;
            float bv = bias[col];
#pragma unroll
            for (int q2 = 0; q2 < 4; ++q2) {
                int row = m0 + wr * 64 + i * 16 + lhi * 4 + q2;
                C[(size_t)row * Ntot + col] = acc[i][j][q2] + bv;
            }
        }
}

// ---------------- FUSED: GRU (blocks 0..63) + scores workers, throttled ----------------
// GRU step: SPECULATIVE burst (plain loads, issued before the counter wait, so
// MALL latency hides under the wait) -> per-wave producer-group poll -> atomic
// cache-bypassing sentinel-retry backstop patches late producers.
__global__ __launch_bounds__(512, 1) void fused_kernel(
    unsigned int* __restrict__ hs32, unsigned int* __restrict__ hrow32,
    const unsigned short* __restrict__ whh_bf,
    const float* __restrict__ gi, const float* __restrict__ b_hh,
    const float* __restrict__ h0,
    const unsigned short* __restrict__ wcls_bf, const float* __restrict__ b_cls,
    float* __restrict__ out, unsigned int* __restrict__ cnt8,
    unsigned int* __restrict__ tileq)
{
    __shared__ __align__(16) char smem[124160];             // union: gru Wl+P / worker dbuf
    __shared__ unsigned short Hs[BATCH][JPB];               // 1KB: hnew bounce
    __shared__ int sTile;

    const int tid = threadIdx.x;
    const int bid = blockIdx.x;
    const int lane = tid & 63, wid = tid >> 6;   // 8 waves
    const int l15 = lane & 15, kg = lane >> 4;

    if (bid < GRU_BLOCKS) {
        // ================= GRU phase =================
        unsigned short (*Wl)[1032] = reinterpret_cast<unsigned short (*)[1032]>(smem);
        float (*P)[32][49] = reinterpret_cast<float (*)[32][49]>(smem + 99072);

        const int j0 = bid * JPB;
        for (int c = tid; c < 48 * 128; c += 512) {
            int row = c >> 7, k8 = (c & 127) * 8;
            int g = row >> 4, jj = row & 15;
            *(short8*)&Wl[row][k8] =
                *(const short8*)(whh_bf + (size_t)(g * HDIM + j0 + jj) * HDIM + k8);
        }
        const int b = tid >> 4, jj = tid & 15;   // one gate item per thread (512 = 32x16)
        const int gj = j0 + jj;
        const float bhr = b_hh[gj];
        const float bhz = b_hh[HDIM + gj];
        const float bhn = b_hh[2 * HDIM + gj];
        float hloc = h0[b * HDIM + gj];
        __syncthreads();

        for (int t = 0; t < T_STEPS; ++t) {
            const size_t tb = (size_t)t * HS_T_STRIDE;
            const float* gr = gi + (size_t)(t * BATCH + b) * (3 * HDIM);
            float xr = gr[gj], xz = gr[HDIM + gj], xn = gr[2 * HDIM + gj];

            if (tid < 256) {   // 4 MFMA waves
                // ---- SPECULATIVE burst: issue before the wait; latency hides under it ----
                const int kq = wid * 256;
                unsigned wv[8][8];
#pragma unroll
                for (int ks = 0; ks < 8; ++ks) {
                    const int wbase = wid * 128 + ks * 16 + kg * 4;
#pragma unroll
                    for (int mi2 = 0; mi2 < 2; ++mi2) {
                        const int bb = mi2 * 16 + l15;
#pragma unroll
                        for (int q = 0; q < 4; ++q)
                            wv[ks][mi2 * 4 + q] = *(const unsigned*)(
                                hs32 + tb + (size_t)(wbase + q) * 32 + bb);
                    }
                }
                // per-wave wait: only THIS wave's 2 producer groups (burst in flight)
                if (t) {
                    const unsigned int* cp = cnt8 + (size_t)t * CNT_STRIDE + 2 * wid;
                    for (;;) {
                        unsigned ok = (lane < 2)
                            ? (__hip_atomic_load(cp + lane, __ATOMIC_RELAXED, __HIP_MEMORY_SCOPE_AGENT) >= 8u ? 1u : 0u)
                            : 1u;
                        if (__all(ok != 0u)) break;
                        __builtin_amdgcn_s_sleep(2);
                    }
                    asm volatile("" ::: "memory");
                }
                // sentinel backstop: cache-bypassing reloads of any still-sentinel word
                for (;;) {
                    int bad = 0;
#pragma unroll
                    for (int ks = 0; ks < 8; ++ks)
#pragma unroll
                        for (int i = 0; i < 8; ++i)
                            bad |= (wv[ks][i] == SENT);
                    if (!__any(bad)) break;
#pragma unroll
                    for (int ks = 0; ks < 8; ++ks)
#pragma unroll
                        for (int i = 0; i < 8; ++i)
                            if (wv[ks][i] == SENT) {
                                const int mi2 = i >> 2, q = i & 3;
                                wv[ks][i] = __hip_atomic_load(
                                    hs32 + tb + (size_t)(wid * 128 + ks * 16 + kg * 4 + q) * 32 + (mi2 * 16 + l15),
                                    __ATOMIC_RELAXED, __HIP_MEMORY_SCOPE_AGENT);
                            }
                }
                f32x4 acc[2][3] = {};
#pragma unroll
                for (int ks = 0; ks < 8; ++ks) {
                    const int kb = kq + ks * 32 + kg * 8;
                    union U8 { unsigned u[4]; short8 s; };
                    short8 ah[2];
#pragma unroll
                    for (int mi2 = 0; mi2 < 2; ++mi2) {
                        U8 x;
#pragma unroll
                        for (int q = 0; q < 4; ++q) x.u[q] = wv[ks][mi2 * 4 + q];
                        ah[mi2] = x.s;
                    }
#pragma unroll
                    for (int fr = 0; fr < 3; ++fr) {
                        short8 bh = *(const short8*)&Wl[fr * 16 + l15][kb];
#pragma unroll
                        for (int mi2 = 0; mi2 < 2; ++mi2)
                            acc[mi2][fr] = __builtin_amdgcn_mfma_f32_16x16x32_bf16(ah[mi2], bh, acc[mi2][fr], 0, 0, 0);
                    }
                }
#pragma unroll
                for (int mi2 = 0; mi2 < 2; ++mi2)
#pragma unroll
                    for (int fr = 0; fr < 3; ++fr)
#pragma unroll
                        for (int q = 0; q < 4; ++q)
                            P[wid][mi2 * 16 + kg * 4 + q][fr * 16 + l15] = acc[mi2][fr][q];
            }
            __syncthreads();

            // gates (one item per thread) -> Hs
            {
                float ghr = 0.f, ghz = 0.f, ghn = 0.f;
#pragma unroll
                for (int w = 0; w < 4; ++w) {
                    ghr += P[w][b][jj];
                    ghz += P[w][b][16 + jj];
                    ghn += P[w][b][32 + jj];
                }
                float r = 1.f / (1.f + __expf(-(xr + ghr + bhr)));
                float z = 1.f / (1.f + __expf(-(xz + ghz + bhz)));
                float n = tanhf(xn + r * (ghn + bhn));
                float hnew = (1.f - z) * n + z * hloc;
                hloc = hnew;
                Hs[b][jj] = f2bf(hnew);
            }
            __syncthreads();

            // wide coherent publish: 64 threads hs32, 64 threads hrow32
            if (tid < 64) {
                const int q = tid >> 3, c = tid & 7;
                u32x4 d;
#pragma unroll
                for (int w2 = 0; w2 < 4; ++w2) {
                    int bb = c * 4 + w2;
                    d[w2] = (unsigned)Hs[bb][2 * q] | ((unsigned)Hs[bb][2 * q + 1] << 16);
                }
                store16_coh(hs32 + (size_t)(t + 1) * HS_T_STRIDE + (size_t)((j0 >> 1) + q) * 32 + c * 4, d);
            } else if (tid < 128) {
                const int i = tid - 64, bb = i >> 1, half = i & 1;
                u32x4 d;
#pragma unroll
                for (int w2 = 0; w2 < 4; ++w2) {
                    int q = half * 4 + w2;
                    d[w2] = (unsigned)Hs[bb][2 * q] | ((unsigned)Hs[bb][2 * q + 1] << 16);
                }
                store16_coh(hrow32 + ((size_t)t * BATCH + bb) * 512 + (j0 >> 1) + half * 4, d);
            }
            __syncthreads();   // drains publish stores (vmcnt(0) before s_barrier)
            if (tid == 0)
                __hip_atomic_fetch_add(cnt8 + (size_t)(t + 1) * CNT_STRIDE + (bid >> 3), 1u,
                                       __ATOMIC_RELAXED, __HIP_MEMORY_SCOPE_AGENT);
        }
    } else if (bid >= GRU_BLOCKS + EARLY_WORKERS) {
        // ---- throttled workers: stay off the fabric until the recurrence is done ----
        if (wid == 0) {
            const unsigned int* cp = cnt8 + (size_t)T_STEPS * CNT_STRIDE;
            for (;;) {
                unsigned v = (lane < 8)
                    ? __hip_atomic_load(cp + lane, __ATOMIC_RELAXED, __HIP_MEMORY_SCOPE_AGENT)
                    : 8u;
                if (__all(v >= 8u)) break;
                __builtin_amdgcn_s_sleep(64);
            }
        }
        __syncthreads();
    }

    // ================= scores worker phase =================
    const unsigned short* hrowA = (const unsigned short*)hrow32;
    const int srow = lane >> 2;
    const int skk = (lane & 3) * 8;

    for (;;) {
        __syncthreads();
        if (tid == 0)
            sTile = (int)__hip_atomic_fetch_add(tileq, 1u, __ATOMIC_RELAXED, __HIP_MEMORY_SCOPE_AGENT);
        __syncthreads();
        const int k = sTile;
        if (k >= N_TILES) break;

        int mi, m0, n0, big;
        if (k < N_BIG) { mi = k / 125; n0 = (k - mi * 125) * 256; m0 = mi * 256; big = 1; }
        else { int idx = k - N_BIG; mi = 5; m0 = 1280 + (idx & 1) * 128; n0 = (idx >> 1) * 256; big = 0; }

        // wait until all h rows for this M-stripe are published
        {
            if (wid == 0) {
                const unsigned int* cp = cnt8 + (size_t)(mi * 8 + 8) * CNT_STRIDE;
                for (;;) {
                    unsigned v = (lane < 8)
                        ? __hip_atomic_load(cp + lane, __ATOMIC_RELAXED, __HIP_MEMORY_SCOPE_AGENT)
                        : 8u;
                    if (__all(v >= 8u)) break;
                    __builtin_amdgcn_s_sleep(32);
                }
            }
            __syncthreads();
            asm volatile("" ::: "memory");
        }

        if (big) {
            // ---- 256x256 tile, 4x2 wave grid (64x128 each), dbuf ----
            const int wm = wid >> 1, wn = wid & 1;
            unsigned short* As0 = (unsigned short*)(smem);
            unsigned short* Bs0 = (unsigned short*)(smem + 16384);
            unsigned short* As1 = (unsigned short*)(smem + 32768);
            unsigned short* Bs1 = (unsigned short*)(smem + 49152);
            f32x4 acc[4][8] = {};

#define STAGE(KT, AB, BB)                                                      \
            {                                                                  \
                const int kb = (KT) * 32;                                      \
                _Pragma("unroll")                                              \
                for (int h2 = 0; h2 < 2; ++h2) {                               \
                    const int i = wid + h2 * 8;                                \
                    const int row = i * 16 + srow;                             \
                    gload_lds16(hrowA + (size_t)(m0 + row) * HDIM + kb + skk, (AB) + i * 512); \
                    gload_lds16(wcls_bf + (size_t)(n0 + row) * HDIM + kb + skk, (BB) + i * 512); \
                }                                                              \
            }
#define COMPUTE(AB, BB)                                                        \
            {                                                                  \
                short8 af[4], bf[8];                                           \
                _Pragma("unroll")                                              \
                for (int i = 0; i < 4; ++i)                                    \
                    af[i] = *(const short8*)((AB) + ((wm * 64 + i * 16 + l15) * 32 + kg * 8)); \
                _Pragma("unroll")                                              \
                for (int j = 0; j < 8; ++j)                                    \
                    bf[j] = *(const short8*)((BB) + ((wn * 128 + j * 16 + l15) * 32 + kg * 8)); \
                _Pragma("unroll")                                              \
                for (int i = 0; i < 4; ++i)                                    \
                    _Pragma("unroll")                                          \
                    for (int j = 0; j < 8; ++j)                                \
                        acc[i][j] = __builtin_amdgcn_mfma_f32_16x16x32_bf16(af[i], bf[j], acc[i][j], 0, 0, 0); \
            }
            STAGE(0, As0, Bs0);
            __syncthreads();
            for (int it = 0; it < 16; ++it) {
                const int kt0 = 2 * it;
                STAGE(kt0 + 1, As1, Bs1);
                COMPUTE(As0, Bs0);
                __syncthreads();
                if (kt0 + 2 < 32) STAGE(kt0 + 2, As0, Bs0);
                COMPUTE(As1, Bs1);
                __syncthreads();
            }
#undef STAGE
#undef COMPUTE
            const int lhi = lane >> 4;
#pragma unroll
            for (int i = 0; i < 4; ++i)
#pragma unroll
                for (int j = 0; j < 8; ++j) {
                    int col = n0 + wn * 128 + j * 16 + l15;
                    float bv = b_cls[col];
#pragma unroll
                    for (int q2 = 0; q2 < 4; ++q2) {
                        int row = m0 + wm * 64 + i * 16 + lhi * 4 + q2;
                        int t = row >> 5, bb = row & 31;
                        __builtin_nontemporal_store(acc[i][j][q2] + bv,
                            &out[(size_t)(bb * T_STEPS + t) * VOCAB + col]);
                    }
                }
        } else {
            // ---- 128x256 tile (tail stripe), 2x4 wave grid (64x64 each), dbuf ----
            const int wm = wid >> 2, wn = wid & 3;
            unsigned short* As0 = (unsigned short*)(smem);            // 8KB
            unsigned short* Bs0 = (unsigned short*)(smem + 8192);     // 16KB
            unsigned short* As1 = (unsigned short*)(smem + 24576);    // 8KB
            unsigned short* Bs1 = (unsigned short*)(smem + 32768);    // 16KB
            f32x4 acc[4][4] = {};

#define STAGE1(KT, AB, BB)                                                     \
            {                                                                  \
                const int kb = (KT) * 32;                                      \
                _Pragma("unroll")                                              \
                for (int h2 = 0; h2 < 3; ++h2) {                               \
                    const int c = wid * 3 + h2;       /* 0..23 */              \
                    if (c < 8) {                                               \
                        const int row = c * 16 + srow;                         \
                        gload_lds16(hrowA + (size_t)(m0 + row) * HDIM + kb + skk, (AB) + c * 512); \
                    } else {                                                   \
                        const int row = (c - 8) * 16 + srow;                   \
                        gload_lds16(wcls_bf + (size_t)(n0 + row) * HDIM + kb + skk, (BB) + (c - 8) * 512); \
                    }                                                          \
                }                                                              \
            }
#define COMPUTE1(AB, BB)                                                       \
            {                                                                  \
                short8 af[4], bf[4];                                           \
                _Pragma("unroll")                                              \
                for (int i = 0; i < 4; ++i)                                    \
                    af[i] = *(const short8*)((AB) + ((wm * 64 + i * 16 + l15) * 32 + kg * 8)); \
                _Pragma("unroll")                                              \
                for (int j = 0; j < 4; ++j)                                    \
                    bf[j] = *(const short8*)((BB) + ((wn * 64 + j * 16 + l15) * 32 + kg * 8)); \
                _Pragma("unroll")                                              \
                for (int i = 0; i < 4; ++i)                                    \
                    _Pragma("unroll")                                          \
                    for (int j = 0; j < 4; ++j)                                \
                        acc[i][j] = __builtin_amdgcn_mfma_f32_16x16x32_bf16(af[i], bf[j], acc[i][j], 0, 0, 0); \
            }
            STAGE1(0, As0, Bs0);
            __syncthreads();
            for (int it = 0; it < 16; ++it) {
                const int kt0 = 2 * it;
                STAGE1(kt0 + 1, As1, Bs1);
                COMPUTE1(As0, Bs0);
                __syncthreads();
                if (kt0 + 2 < 32) STAGE1(kt0 + 2, As0, Bs0);
                COMPUTE1(As1, Bs1);
                __syncthreads();
            }
#undef STAGE1
#undef COMPUTE1
            const int lhi = lane >> 4;
#pragma unroll
            for (int i = 0; i < 4; ++i)
#pragma unroll
                for (int j = 0; j < 4; ++j) {
                    int col = n0 + wn * 64 + j * 16 + l15;
                    float bv = b_cls[col];
#pragma unroll
                    for (int q2 = 0; q2 < 4; ++q2) {
                        int row = m0 + wm * 64 + i * 16 + lhi * 4 + q2;
                        int t = row >> 5, bb = row & 31;
                        __builtin_nontemporal_store(acc[i][j][q2] + bv,
                            &out[(size_t)(bb * T_STEPS + t) * VOCAB + col]);
                    }
                }
        }
    }
}

extern "C" void kernel_launch(void* const* d_in, const int* in_sizes, int n_in,
                              void* d_out, int out_size, void* d_ws, size_t ws_size,
                              hipStream_t stream) {
    const float* h0    = (const float*)d_in[0];
    const int*   tseq  = (const int*)d_in[1];
    const float* emb   = (const float*)d_in[2];
    const float* w_ih  = (const float*)d_in[3];
    const float* w_hh  = (const float*)d_in[4];
    const float* b_ih  = (const float*)d_in[5];
    const float* b_hh  = (const float*)d_in[6];
    const float* w_cls = (const float*)d_in[7];
    const float* b_cls = (const float*)d_in[8];
    float* out = (float*)d_out;

    char* w = (char*)d_ws;
    unsigned short* wcls_bf = (unsigned short*)w; w += (size_t)VOCAB * HDIM * 2;
    unsigned short* wih_bf  = (unsigned short*)w; w += (size_t)3 * HDIM * EDIM * 2;
    unsigned short* whh_bf  = (unsigned short*)w; w += (size_t)3 * HDIM * HDIM * 2;
    unsigned short* x_bf    = (unsigned short*)w; w += (size_t)T_STEPS * BATCH * EDIM * 2;
    unsigned int*   hs32    = (unsigned int*)w;   w += (size_t)(T_STEPS + 1) * HS_T_STRIDE * 4;
    unsigned int*   hrow32  = (unsigned int*)w;   w += (size_t)T_STEPS * BATCH * 512 * 4;
    float* gi               = (float*)w;          w += (size_t)T_STEPS * BATCH * 3 * HDIM * 4;
    unsigned int* cnt8      = (unsigned int*)w;   w += 8192;
    unsigned int* tileq     = cnt8 + 1024;        // own 64B line, zeroed with cnt8

    prep_kernel<<<2048, 256, 0, stream>>>(h0, tseq, emb, w_ih, w_hh, w_cls,
                                          wcls_bf, wih_bf, whh_bf, x_bf, hs32, cnt8);

    // GI = X @ W_ih^T + b_ih : M=1536, N=3072, K=512  (288 wgs, %8==0)
    gemm_gi<<<(T_STEPS * BATCH / 128) * (3 * HDIM / 128), 256, 0, stream>>>(
        x_bf, wih_bf, b_ih, gi, EDIM, 3 * HDIM, T_STEPS * BATCH / 128);

    // fused GRU (speculative-burst) + throttled overlapped scores GEMM
    fused_kernel<<<256, 512, 0, stream>>>(hs32, hrow32, whh_bf, gi, b_hh, h0,
                                          wcls_bf, b_cls, out, cnt8, tileq);
}

// Round 22
// 344.101 us; speedup vs baseline: 1.2486x; 1.2486x over previous
//
#include <hip/hip_runtime.h>
#include <hip/hip_bf16.h>

typedef __attribute__((ext_vector_type(8))) short short8;
typedef __attribute__((ext_vector_type(4))) float f32x4;
typedef __attribute__((ext_vector_type(4))) unsigned int u32x4;

#define T_STEPS 48
#define BATCH 32
#define EDIM 512
#define HDIM 1024
#define VOCAB 32000
#define GRU_BLOCKS 64
#define JPB 16
#define SENT 0x7FFF7FFFu
#define N_BIG 625                  // stripes 0..4: 256x256 tiles (5 x 125)
#define N_TILES 875                // + stripe 5 as 250 tiles of 128x256
#define CNT_STRIDE 16              // uints per t-slot (64B padded)
#define EARLY_WORKERS 96           // blocks 64..159 work during gru; 160+ throttled

// packed h storage (hi-plane only): uint words, [t(49)][k_pair(512)][b(32)]
#define HS_T_STRIDE 16384          // uints per t-slot

__device__ __forceinline__ unsigned short f2bf(float f) {
    __hip_bfloat16 h = __float2bfloat16(f);
    return *reinterpret_cast<unsigned short*>(&h);
}
__device__ __forceinline__ float bf2f(unsigned short u) {
    union { unsigned int i; float f; } v;
    v.i = ((unsigned int)u) << 16;
    return v.f;
}

typedef __attribute__((address_space(1))) const void GAS;
typedef __attribute__((address_space(3))) void LAS;
__device__ __forceinline__ void gload_lds16(const unsigned short* g, unsigned short* l) {
    __builtin_amdgcn_global_load_lds((GAS*)g, (LAS*)(unsigned)(uintptr_t)l, 16, 0, 0);
}

// coherent (cross-XCD visible) 16B store
__device__ __forceinline__ void store16_coh(unsigned int* p, u32x4 v) {
    asm volatile("global_store_dwordx4 %0, %1, off sc0 sc1"
                 :: "v"((unsigned long long)(uintptr_t)p), "v"(v) : "memory");
}

// ---------------- prep: conversions, gather, h0 pack, sentinel fill, cnt/queue zero ----------------
__global__ __launch_bounds__(256) void prep_kernel(
    const float* __restrict__ h0, const int* __restrict__ tseq,
    const float* __restrict__ emb, const float* __restrict__ w_ih,
    const float* __restrict__ w_hh, const float* __restrict__ w_cls,
    unsigned short* __restrict__ wcls_bf, unsigned short* __restrict__ wih_bf,
    unsigned short* __restrict__ whh_bf, unsigned short* __restrict__ x_bf,
    unsigned int* __restrict__ hs32, unsigned int* __restrict__ cnt8)
{
    const long R0 = (long)VOCAB * HDIM / 4;           // w_cls
    const long R1 = (long)3 * HDIM * EDIM / 4;        // w_ih
    const long R2 = (long)3 * HDIM * HDIM / 4;        // w_hh (hi only)
    const long R3 = (long)T_STEPS * BATCH * EDIM / 4; // X gather
    const long R4 = (long)HS_T_STRIDE;                // h0 -> packed slot 0
    const long R5 = (long)T_STEPS * HS_T_STRIDE / 4;  // sentinel fill t=1..48 (uint4)
    const long R6 = 512;                              // cnt8(padded)+tileq zero: 2048 uints
    const long total = R0 + R1 + R2 + R3 + R4 + R5 + R6;

    for (long i = (long)blockIdx.x * blockDim.x + threadIdx.x; i < total;
         i += (long)gridDim.x * blockDim.x) {
        if (i < R0) {
            float4 v = reinterpret_cast<const float4*>(w_cls)[i];
            ushort4 u = { f2bf(v.x), f2bf(v.y), f2bf(v.z), f2bf(v.w) };
            *reinterpret_cast<ushort4*>(wcls_bf + i * 4) = u;
        } else if (i < R0 + R1) {
            long j = i - R0;
            float4 v = reinterpret_cast<const float4*>(w_ih)[j];
            ushort4 u = { f2bf(v.x), f2bf(v.y), f2bf(v.z), f2bf(v.w) };
            *reinterpret_cast<ushort4*>(wih_bf + j * 4) = u;
        } else if (i < R0 + R1 + R2) {
            long j = i - R0 - R1;
            float4 v = reinterpret_cast<const float4*>(w_hh)[j];
            ushort4 u = { f2bf(v.x), f2bf(v.y), f2bf(v.z), f2bf(v.w) };
            *reinterpret_cast<ushort4*>(whh_bf + j * 4) = u;
        } else if (i < R0 + R1 + R2 + R3) {
            long j = i - R0 - R1 - R2;
            int m = (int)(j >> 7);
            int kk4 = (int)(j & 127);
            int t = m >> 5, b = m & 31;
            int tok = tseq[b * T_STEPS + t];
            float4 v = reinterpret_cast<const float4*>(emb)[(long)tok * (EDIM / 4) + kk4];
            ushort4 u = { f2bf(v.x), f2bf(v.y), f2bf(v.z), f2bf(v.w) };
            *reinterpret_cast<ushort4*>(x_bf + (long)m * EDIM + kk4 * 4) = u;
        } else if (i < R0 + R1 + R2 + R3 + R4) {
            long j = i - R0 - R1 - R2 - R3;       // uint index: w*32 + b
            int w = (int)(j >> 5), b = (int)(j & 31);
            unsigned short a = f2bf(h0[b * HDIM + 2 * w]);
            unsigned short c = f2bf(h0[b * HDIM + 2 * w + 1]);
            hs32[j] = (unsigned)a | ((unsigned)c << 16);
        } else if (i < R0 + R1 + R2 + R3 + R4 + R5) {
            long j = i - R0 - R1 - R2 - R3 - R4;
            uint4 s = { SENT, SENT, SENT, SENT };
            reinterpret_cast<uint4*>(hs32 + HS_T_STRIDE)[j] = s;   // t=1..48
        } else {
            long j = i - R0 - R1 - R2 - R3 - R4 - R5;
            uint4 z = { 0u, 0u, 0u, 0u };
            reinterpret_cast<uint4*>(cnt8)[j] = z;
        }
    }
}

// ---------------- GI GEMM: gi = X @ W_ih^T + b_ih (proven gload_lds 128x128) ----------------
__global__ __launch_bounds__(256) void gemm_gi(
    const unsigned short* __restrict__ A, const unsigned short* __restrict__ B,
    const float* __restrict__ bias, float* __restrict__ C, int K, int Ntot, int nM)
{
    const int nwg = gridDim.x;
    const int lin = blockIdx.x;
    const int q = nwg >> 3;
    const int wg = (lin & 7) * q + (lin >> 3);
    const int mi = wg % nM, ni = wg / nM;
    const int m0 = mi * 128, n0 = ni * 128;

    const int tid = threadIdx.x;
    const int lane = tid & 63;
    const int wid = tid >> 6;
    const int wr = wid >> 1, wc = wid & 1;

    __shared__ __align__(16) unsigned short As[128 * 32];
    __shared__ __align__(16) unsigned short Bs[128 * 32];

    f32x4 acc[4][4] = {};
    const int NT = K >> 5;
    const int srow = (lane >> 2);
    const int skk = (lane & 3) * 8;

    for (int kt = 0; kt < NT; ++kt) {
        __syncthreads();
        {
            const int kb = kt * 32;
#pragma unroll
            for (int h2 = 0; h2 < 2; ++h2) {
                const int i = wid + h2 * 4;
                const int row = i * 16 + srow;
                gload_lds16(A + (size_t)(m0 + row) * K + kb + skk, As + i * 512);
                gload_lds16(B + (size_t)(n0 + row) * K + kb + skk, Bs + i * 512);
            }
        }
        __syncthreads();

        const int kg = lane >> 4;
        const int l15 = lane & 15;
        short8 af[4], bf[4];
#pragma unroll
        for (int i = 0; i < 4; ++i) {
            af[i] = *(const short8*)(As + ((wr * 64 + i * 16 + l15) * 32 + kg * 8));
            bf[i] = *(const short8*)(Bs + ((wc * 64 + i * 16 + l15) * 32 + kg * 8));
        }
#pragma unroll
        for (int i = 0; i < 4; ++i)
#pragma unroll
            for (int j = 0; j < 4; ++j)
                acc[i][j] = __builtin_amdgcn_mfma_f32_16x16x32_bf16(af[i], bf[j], acc[i][j], 0, 0, 0);
    }

    const int l15 = lane & 15, lhi = lane >> 4;
#pragma unroll
    for (int i = 0; i < 4; ++i)
#pragma unroll
        for (int j = 0; j < 4; ++j) {
            int col = n0 + wc * 64 + j * 16 + l15;
            float bv = bias[col];
#pragma unroll
            for (int q2 = 0; q2 < 4; ++q2) {
                int row = m0 + wr * 64 + i * 16 + lhi * 4 + q2;
                C[(size_t)row * Ntot + col] = acc[i][j][q2] + bv;
            }
        }
}

// ---------------- FUSED: GRU (blocks 0..63) + scores workers, throttled ----------------
// Stripes 0..4: 256x256 tiles (dbuf). Stripe 5 (only ready at gru end): 250
// tiles of 128x256 for a ~2x shorter tail. Per-wave split-K producer-group poll.
__global__ __launch_bounds__(512, 1) void fused_kernel(
    unsigned int* __restrict__ hs32, unsigned int* __restrict__ hrow32,
    const unsigned short* __restrict__ whh_bf,
    const float* __restrict__ gi, const float* __restrict__ b_hh,
    const float* __restrict__ h0,
    const unsigned short* __restrict__ wcls_bf, const float* __restrict__ b_cls,
    float* __restrict__ out, unsigned int* __restrict__ cnt8,
    unsigned int* __restrict__ tileq)
{
    __shared__ __align__(16) char smem[124160];             // union: gru Wl+P / worker dbuf
    __shared__ unsigned short Hs[BATCH][JPB];               // 1KB: hnew bounce
    __shared__ int sTile;

    const int tid = threadIdx.x;
    const int bid = blockIdx.x;
    const int lane = tid & 63, wid = tid >> 6;   // 8 waves
    const int l15 = lane & 15, kg = lane >> 4;

    if (bid < GRU_BLOCKS) {
        // ================= GRU phase =================
        unsigned short (*Wl)[1032] = reinterpret_cast<unsigned short (*)[1032]>(smem);
        float (*P)[32][49] = reinterpret_cast<float (*)[32][49]>(smem + 99072);

        const int j0 = bid * JPB;
        for (int c = tid; c < 48 * 128; c += 512) {
            int row = c >> 7, k8 = (c & 127) * 8;
            int g = row >> 4, jj = row & 15;
            *(short8*)&Wl[row][k8] =
                *(const short8*)(whh_bf + (size_t)(g * HDIM + j0 + jj) * HDIM + k8);
        }
        const int b = tid >> 4, jj = tid & 15;   // one gate item per thread (512 = 32x16)
        const int gj = j0 + jj;
        const float bhr = b_hh[gj];
        const float bhz = b_hh[HDIM + gj];
        const float bhn = b_hh[2 * HDIM + gj];
        float hloc = h0[b * HDIM + gj];
        __syncthreads();

        for (int t = 0; t < T_STEPS; ++t) {
            const size_t tb = (size_t)t * HS_T_STRIDE;
            const float* gr = gi + (size_t)(t * BATCH + b) * (3 * HDIM);
            float xr = gr[gj], xz = gr[HDIM + gj], xn = gr[2 * HDIM + gj];

            if (tid < 256) {   // 4 MFMA waves
                // per-wave wait: only THIS wave's 2 producer groups
                if (t) {
                    const unsigned int* cp = cnt8 + (size_t)t * CNT_STRIDE + 2 * wid;
                    for (;;) {
                        unsigned ok = (lane < 2)
                            ? (__hip_atomic_load(cp + lane, __ATOMIC_RELAXED, __HIP_MEMORY_SCOPE_AGENT) >= 8u ? 1u : 0u)
                            : 1u;
                        if (__all(ok != 0u)) break;
                        __builtin_amdgcn_s_sleep(2);
                    }
                    asm volatile("" ::: "memory");
                }

                const int kq = wid * 256;
                unsigned wv[8][8];
#pragma unroll
                for (int ks = 0; ks < 8; ++ks) {
                    const int wbase = wid * 128 + ks * 16 + kg * 4;
#pragma unroll
                    for (int mi2 = 0; mi2 < 2; ++mi2) {
                        const int bb = mi2 * 16 + l15;
#pragma unroll
                        for (int q = 0; q < 4; ++q)
                            wv[ks][mi2 * 4 + q] = *(const unsigned*)(
                                hs32 + tb + (size_t)(wbase + q) * 32 + bb);
                    }
                }
                for (;;) {   // sentinel backstop
                    int bad = 0;
#pragma unroll
                    for (int ks = 0; ks < 8; ++ks)
#pragma unroll
                        for (int i = 0; i < 8; ++i)
                            bad |= (wv[ks][i] == SENT);
                    if (!__any(bad)) break;
                    __builtin_amdgcn_s_sleep(1);
#pragma unroll
                    for (int ks = 0; ks < 8; ++ks)
#pragma unroll
                        for (int i = 0; i < 8; ++i)
                            if (wv[ks][i] == SENT) {
                                const int mi2 = i >> 2, q = i & 3;
                                wv[ks][i] = __hip_atomic_load(
                                    hs32 + tb + (size_t)(wid * 128 + ks * 16 + kg * 4 + q) * 32 + (mi2 * 16 + l15),
                                    __ATOMIC_RELAXED, __HIP_MEMORY_SCOPE_AGENT);
                            }
                }
                f32x4 acc[2][3] = {};
#pragma unroll
                for (int ks = 0; ks < 8; ++ks) {
                    const int kb = kq + ks * 32 + kg * 8;
                    union U8 { unsigned u[4]; short8 s; };
                    short8 ah[2];
#pragma unroll
                    for (int mi2 = 0; mi2 < 2; ++mi2) {
                        U8 x;
#pragma unroll
                        for (int q = 0; q < 4; ++q) x.u[q] = wv[ks][mi2 * 4 + q];
                        ah[mi2] = x.s;
                    }
#pragma unroll
                    for (int fr = 0; fr < 3; ++fr) {
                        short8 bh = *(const short8*)&Wl[fr * 16 + l15][kb];
#pragma unroll
                        for (int mi2 = 0; mi2 < 2; ++mi2)
                            acc[mi2][fr] = __builtin_amdgcn_mfma_f32_16x16x32_bf16(ah[mi2], bh, acc[mi2][fr], 0, 0, 0);
                    }
                }
#pragma unroll
                for (int mi2 = 0; mi2 < 2; ++mi2)
#pragma unroll
                    for (int fr = 0; fr < 3; ++fr)
#pragma unroll
                        for (int q = 0; q < 4; ++q)
                            P[wid][mi2 * 16 + kg * 4 + q][fr * 16 + l15] = acc[mi2][fr][q];
            }
            __syncthreads();

            // gates (one item per thread) -> Hs
            {
                float ghr = 0.f, ghz = 0.f, ghn = 0.f;
#pragma unroll
                for (int w = 0; w < 4; ++w) {
                    ghr += P[w][b][jj];
                    ghz += P[w][b][16 + jj];
                    ghn += P[w][b][32 + jj];
                }
                float r = 1.f / (1.f + __expf(-(xr + ghr + bhr)));
                float z = 1.f / (1.f + __expf(-(xz + ghz + bhz)));
                float n = tanhf(xn + r * (ghn + bhn));
                float hnew = (1.f - z) * n + z * hloc;
                hloc = hnew;
                Hs[b][jj] = f2bf(hnew);
            }
            __syncthreads();

            // wide coherent publish: 64 threads hs32, 64 threads hrow32
            if (tid < 64) {
                const int q = tid >> 3, c = tid & 7;
                u32x4 d;
#pragma unroll
                for (int w2 = 0; w2 < 4; ++w2) {
                    int bb = c * 4 + w2;
                    d[w2] = (unsigned)Hs[bb][2 * q] | ((unsigned)Hs[bb][2 * q + 1] << 16);
                }
                store16_coh(hs32 + (size_t)(t + 1) * HS_T_STRIDE + (size_t)((j0 >> 1) + q) * 32 + c * 4, d);
            } else if (tid < 128) {
                const int i = tid - 64, bb = i >> 1, half = i & 1;
                u32x4 d;
#pragma unroll
                for (int w2 = 0; w2 < 4; ++w2) {
                    int q = half * 4 + w2;
                    d[w2] = (unsigned)Hs[bb][2 * q] | ((unsigned)Hs[bb][2 * q + 1] << 16);
                }
                store16_coh(hrow32 + ((size_t)t * BATCH + bb) * 512 + (j0 >> 1) + half * 4, d);
            }
            __syncthreads();   // drains publish stores (vmcnt(0) before s_barrier)
            if (tid == 0)
                __hip_atomic_fetch_add(cnt8 + (size_t)(t + 1) * CNT_STRIDE + (bid >> 3), 1u,
                                       __ATOMIC_RELAXED, __HIP_MEMORY_SCOPE_AGENT);
        }
    } else if (bid >= GRU_BLOCKS + EARLY_WORKERS) {
        // ---- throttled workers: stay off the fabric until the recurrence is done ----
        if (wid == 0) {
            const unsigned int* cp = cnt8 + (size_t)T_STEPS * CNT_STRIDE;
            for (;;) {
                unsigned v = (lane < 8)
                    ? __hip_atomic_load(cp + lane, __ATOMIC_RELAXED, __HIP_MEMORY_SCOPE_AGENT)
                    : 8u;
                if (__all(v >= 8u)) break;
                __builtin_amdgcn_s_sleep(64);
            }
        }
        __syncthreads();
    }

    // ================= scores worker phase =================
    const unsigned short* hrowA = (const unsigned short*)hrow32;
    const int srow = lane >> 2;
    const int skk = (lane & 3) * 8;

    for (;;) {
        __syncthreads();
        if (tid == 0)
            sTile = (int)__hip_atomic_fetch_add(tileq, 1u, __ATOMIC_RELAXED, __HIP_MEMORY_SCOPE_AGENT);
        __syncthreads();
        const int k = sTile;
        if (k >= N_TILES) break;

        int mi, m0, n0, big;
        if (k < N_BIG) { mi = k / 125; n0 = (k - mi * 125) * 256; m0 = mi * 256; big = 1; }
        else { int idx = k - N_BIG; mi = 5; m0 = 1280 + (idx & 1) * 128; n0 = (idx >> 1) * 256; big = 0; }

        // wait until all h rows for this M-stripe are published
        {
            if (wid == 0) {
                const unsigned int* cp = cnt8 + (size_t)(mi * 8 + 8) * CNT_STRIDE;
                for (;;) {
                    unsigned v = (lane < 8)
                        ? __hip_atomic_load(cp + lane, __ATOMIC_RELAXED, __HIP_MEMORY_SCOPE_AGENT)
                        : 8u;
                    if (__all(v >= 8u)) break;
                    __builtin_amdgcn_s_sleep(32);
                }
            }
            __syncthreads();
            asm volatile("" ::: "memory");
        }

        if (big) {
            // ---- 256x256 tile, 4x2 wave grid (64x128 each), dbuf ----
            const int wm = wid >> 1, wn = wid & 1;
            unsigned short* As0 = (unsigned short*)(smem);
            unsigned short* Bs0 = (unsigned short*)(smem + 16384);
            unsigned short* As1 = (unsigned short*)(smem + 32768);
            unsigned short* Bs1 = (unsigned short*)(smem + 49152);
            f32x4 acc[4][8] = {};

#define STAGE(KT, AB, BB)                                                      \
            {                                                                  \
                const int kb = (KT) * 32;                                      \
                _Pragma("unroll")                                              \
                for (int h2 = 0; h2 < 2; ++h2) {                               \
                    const int i = wid + h2 * 8;                                \
                    const int row = i * 16 + srow;                             \
                    gload_lds16(hrowA + (size_t)(m0 + row) * HDIM + kb + skk, (AB) + i * 512); \
                    gload_lds16(wcls_bf + (size_t)(n0 + row) * HDIM + kb + skk, (BB) + i * 512); \
                }                                                              \
            }
#define COMPUTE(AB, BB)                                                        \
            {                                                                  \
                short8 af[4], bf[8];                                           \
                _Pragma("unroll")                                              \
                for (int i = 0; i < 4; ++i)                                    \
                    af[i] = *(const short8*)((AB) + ((wm * 64 + i * 16 + l15) * 32 + kg * 8)); \
                _Pragma("unroll")                                              \
                for (int j = 0; j < 8; ++j)                                    \
                    bf[j] = *(const short8*)((BB) + ((wn * 128 + j * 16 + l15) * 32 + kg * 8)); \
                _Pragma("unroll")                                              \
                for (int i = 0; i < 4; ++i)                                    \
                    _Pragma("unroll")                                          \
                    for (int j = 0; j < 8; ++j)                                \
                        acc[i][j] = __builtin_amdgcn_mfma_f32_16x16x32_bf16(af[i], bf[j], acc[i][j], 0, 0, 0); \
            }
            STAGE(0, As0, Bs0);
            __syncthreads();
            for (int it = 0; it < 16; ++it) {
                const int kt0 = 2 * it;
                STAGE(kt0 + 1, As1, Bs1);
                COMPUTE(As0, Bs0);
                __syncthreads();
                if (kt0 + 2 < 32) STAGE(kt0 + 2, As0, Bs0);
                COMPUTE(As1, Bs1);
                __syncthreads();
            }
#undef STAGE
#undef COMPUTE
            const int lhi = lane >> 4;
#pragma unroll
            for (int i = 0; i < 4; ++i)
#pragma unroll
                for (int j = 0; j < 8; ++j) {
                    int col = n0 + wn * 128 + j * 16 + l15;
                    float bv = b_cls[col];
#pragma unroll
                    for (int q2 = 0; q2 < 4; ++q2) {
                        int row = m0 + wm * 64 + i * 16 + lhi * 4 + q2;
                        int t = row >> 5, bb = row & 31;
                        __builtin_nontemporal_store(acc[i][j][q2] + bv,
                            &out[(size_t)(bb * T_STEPS + t) * VOCAB + col]);
                    }
                }
        } else {
            // ---- 128x256 tile (tail stripe), 2x4 wave grid (64x64 each), dbuf ----
            const int wm = wid >> 2, wn = wid & 3;
            unsigned short* As0 = (unsigned short*)(smem);            // 8KB
            unsigned short* Bs0 = (unsigned short*)(smem + 8192);     // 16KB
            unsigned short* As1 = (unsigned short*)(smem + 24576);    // 8KB
            unsigned short* Bs1 = (unsigned short*)(smem + 32768);    // 16KB
            f32x4 acc[4][4] = {};

#define STAGE1(KT, AB, BB)                                                     \
            {                                                                  \
                const int kb = (KT) * 32;                                      \
                _Pragma("unroll")                                              \
                for (int h2 = 0; h2 < 3; ++h2) {                               \
                    const int c = wid * 3 + h2;       /* 0..23 */              \
                    if (c < 8) {                                               \
                        const int row = c * 16 + srow;                         \
                        gload_lds16(hrowA + (size_t)(m0 + row) * HDIM + kb + skk, (AB) + c * 512); \
                    } else {                                                   \
                        const int row = (c - 8) * 16 + srow;                   \
                        gload_lds16(wcls_bf + (size_t)(n0 + row) * HDIM + kb + skk, (BB) + (c - 8) * 512); \
                    }                                                          \
                }                                                              \
            }
#define COMPUTE1(AB, BB)                                                       \
            {                                                                  \
                short8 af[4], bf[4];                                           \
                _Pragma("unroll")                                              \
                for (int i = 0; i < 4; ++i)                                    \
                    af[i] = *(const short8*)((AB) + ((wm * 64 + i * 16 + l15) * 32 + kg * 8)); \
                _Pragma("unroll")                                              \
                for (int j = 0; j < 4; ++j)                                    \
                    bf[j] = *(const short8*)((BB) + ((wn * 64 + j * 16 + l15) * 32 + kg * 8)); \
                _Pragma("unroll")                                              \
                for (int i = 0; i < 4; ++i)                                    \
                    _Pragma("unroll")                                          \
                    for (int j = 0; j < 4; ++j)                                \
                        acc[i][j] = __builtin_amdgcn_mfma_f32_16x16x32_bf16(af[i], bf[j], acc[i][j], 0, 0, 0); \
            }
            STAGE1(0, As0, Bs0);
            __syncthreads();
            for (int it = 0; it < 16; ++it) {
                const int kt0 = 2 * it;
                STAGE1(kt0 + 1, As1, Bs1);
                COMPUTE1(As0, Bs0);
                __syncthreads();
                if (kt0 + 2 < 32) STAGE1(kt0 + 2, As0, Bs0);
                COMPUTE1(As1, Bs1);
                __syncthreads();
            }
#undef STAGE1
#undef COMPUTE1
            const int lhi = lane >> 4;
#pragma unroll
            for (int i = 0; i < 4; ++i)
#pragma unroll
                for (int j = 0; j < 4; ++j) {
                    int col = n0 + wn * 64 + j * 16 + l15;
                    float bv = b_cls[col];
#pragma unroll
                    for (int q2 = 0; q2 < 4; ++q2) {
                        int row = m0 + wm * 64 + i * 16 + lhi * 4 + q2;
                        int t = row >> 5, bb = row & 31;
                        __builtin_nontemporal_store(acc[i][j][q2] + bv,
                            &out[(size_t)(bb * T_STEPS + t) * VOCAB + col]);
                    }
                }
        }
    }
}

extern "C" void kernel_launch(void* const* d_in, const int* in_sizes, int n_in,
                              void* d_out, int out_size, void* d_ws, size_t ws_size,
                              hipStream_t stream) {
    const float* h0    = (const float*)d_in[0];
    const int*   tseq  = (const int*)d_in[1];
    const float* emb   = (const float*)d_in[2];
    const float* w_ih  = (const float*)d_in[3];
    const float* w_hh  = (const float*)d_in[4];
    const float* b_ih  = (const float*)d_in[5];
    const float* b_hh  = (const float*)d_in[6];
    const float* w_cls = (const float*)d_in[7];
    const float* b_cls = (const float*)d_in[8];
    float* out = (float*)d_out;

    char* w = (char*)d_ws;
    unsigned short* wcls_bf = (unsigned short*)w; w += (size_t)VOCAB * HDIM * 2;
    unsigned short* wih_bf  = (unsigned short*)w; w += (size_t)3 * HDIM * EDIM * 2;
    unsigned short* whh_bf  = (unsigned short*)w; w += (size_t)3 * HDIM * HDIM * 2;
    unsigned short* x_bf    = (unsigned short*)w; w += (size_t)T_STEPS * BATCH * EDIM * 2;
    unsigned int*   hs32    = (unsigned int*)w;   w += (size_t)(T_STEPS + 1) * HS_T_STRIDE * 4;
    unsigned int*   hrow32  = (unsigned int*)w;   w += (size_t)T_STEPS * BATCH * 512 * 4;
    float* gi               = (float*)w;          w += (size_t)T_STEPS * BATCH * 3 * HDIM * 4;
    unsigned int* cnt8      = (unsigned int*)w;   w += 8192;
    unsigned int* tileq     = cnt8 + 1024;        // own 64B line, zeroed with cnt8

    prep_kernel<<<2048, 256, 0, stream>>>(h0, tseq, emb, w_ih, w_hh, w_cls,
                                          wcls_bf, wih_bf, whh_bf, x_bf, hs32, cnt8);

    // GI = X @ W_ih^T + b_ih : M=1536, N=3072, K=512  (288 wgs, %8==0)
    gemm_gi<<<(T_STEPS * BATCH / 128) * (3 * HDIM / 128), 256, 0, stream>>>(
        x_bf, wih_bf, b_ih, gi, EDIM, 3 * HDIM, T_STEPS * BATCH / 128);

    // fused GRU + throttled overlapped scores GEMM: 256 blocks (1/CU, all co-resident)
    fused_kernel<<<256, 512, 0, stream>>>(hs32, hrow32, whh_bf, gi, b_hh, h0,
                                          wcls_bf, b_cls, out, cnt8, tileq);
}

// Round 23
// 330.797 us; speedup vs baseline: 1.2988x; 1.0402x over previous
//
#include <hip/hip_runtime.h>
#include <hip/hip_bf16.h>

typedef __attribute__((ext_vector_type(8))) short short8;
typedef __attribute__((ext_vector_type(4))) float f32x4;
typedef __attribute__((ext_vector_type(4))) unsigned int u32x4;

#define T_STEPS 48
#define BATCH 32
#define EDIM 512
#define HDIM 1024
#define VOCAB 32000
#define GRU_BLOCKS 64
#define JPB 16
#define SENT 0x7FFF7FFFu
#define N_BIG 625                  // stripes 0..4: 256x256 tiles (5 x 125)
#define N_TILES 875                // + stripe 5 as 250 tiles of 128x256
#define CNT_STRIDE 16              // uints per t-slot (64B padded)
#define EARLY_WORKERS 96           // blocks 64..159 work during gru; 160+ throttled

// packed h storage (hi-plane only): uint words, [t(49)][k_pair(512)][b(32)]
#define HS_T_STRIDE 16384          // uints per t-slot

__device__ __forceinline__ unsigned short f2bf(float f) {
    __hip_bfloat16 h = __float2bfloat16(f);
    return *reinterpret_cast<unsigned short*>(&h);
}
__device__ __forceinline__ float bf2f(unsigned short u) {
    union { unsigned int i; float f; } v;
    v.i = ((unsigned int)u) << 16;
    return v.f;
}

typedef __attribute__((address_space(1))) const void GAS;
typedef __attribute__((address_space(3))) void LAS;
__device__ __forceinline__ void gload_lds16(const unsigned short* g, unsigned short* l) {
    __builtin_amdgcn_global_load_lds((GAS*)g, (LAS*)(unsigned)(uintptr_t)l, 16, 0, 0);
}

// coherent (cross-XCD visible) 16B store
__device__ __forceinline__ void store16_coh(unsigned int* p, u32x4 v) {
    asm volatile("global_store_dwordx4 %0, %1, off sc0 sc1"
                 :: "v"((unsigned long long)(uintptr_t)p), "v"(v) : "memory");
}

// ---------------- prep: small conversions, gather, h0 pack, sentinel fill, cnt zero ----------------
// (w_cls conversion moved into fused_kernel's worker blocks)
__global__ __launch_bounds__(256) void prep_kernel(
    const float* __restrict__ h0, const int* __restrict__ tseq,
    const float* __restrict__ emb, const float* __restrict__ w_ih,
    const float* __restrict__ w_hh,
    unsigned short* __restrict__ wih_bf, unsigned short* __restrict__ whh_bf,
    unsigned short* __restrict__ x_bf,
    unsigned int* __restrict__ hs32, unsigned int* __restrict__ cnt8)
{
    const long R1 = (long)3 * HDIM * EDIM / 4;        // w_ih
    const long R2 = (long)3 * HDIM * HDIM / 4;        // w_hh (hi only)
    const long R3 = (long)T_STEPS * BATCH * EDIM / 4; // X gather
    const long R4 = (long)HS_T_STRIDE;                // h0 -> packed slot 0
    const long R5 = (long)T_STEPS * HS_T_STRIDE / 4;  // sentinel fill t=1..48 (uint4)
    const long R6 = 512;                              // cnt8(padded)+tileq+wcnt zero: 2048 uints
    const long total = R1 + R2 + R3 + R4 + R5 + R6;

    for (long i = (long)blockIdx.x * blockDim.x + threadIdx.x; i < total;
         i += (long)gridDim.x * blockDim.x) {
        if (i < R1) {
            long j = i;
            float4 v = reinterpret_cast<const float4*>(w_ih)[j];
            ushort4 u = { f2bf(v.x), f2bf(v.y), f2bf(v.z), f2bf(v.w) };
            *reinterpret_cast<ushort4*>(wih_bf + j * 4) = u;
        } else if (i < R1 + R2) {
            long j = i - R1;
            float4 v = reinterpret_cast<const float4*>(w_hh)[j];
            ushort4 u = { f2bf(v.x), f2bf(v.y), f2bf(v.z), f2bf(v.w) };
            *reinterpret_cast<ushort4*>(whh_bf + j * 4) = u;
        } else if (i < R1 + R2 + R3) {
            long j = i - R1 - R2;
            int m = (int)(j >> 7);
            int kk4 = (int)(j & 127);
            int t = m >> 5, b = m & 31;
            int tok = tseq[b * T_STEPS + t];
            float4 v = reinterpret_cast<const float4*>(emb)[(long)tok * (EDIM / 4) + kk4];
            ushort4 u = { f2bf(v.x), f2bf(v.y), f2bf(v.z), f2bf(v.w) };
            *reinterpret_cast<ushort4*>(x_bf + (long)m * EDIM + kk4 * 4) = u;
        } else if (i < R1 + R2 + R3 + R4) {
            long j = i - R1 - R2 - R3;            // uint index: w*32 + b
            int w = (int)(j >> 5), b = (int)(j & 31);
            unsigned short a = f2bf(h0[b * HDIM + 2 * w]);
            unsigned short c = f2bf(h0[b * HDIM + 2 * w + 1]);
            hs32[j] = (unsigned)a | ((unsigned)c << 16);
        } else if (i < R1 + R2 + R3 + R4 + R5) {
            long j = i - R1 - R2 - R3 - R4;
            uint4 s = { SENT, SENT, SENT, SENT };
            reinterpret_cast<uint4*>(hs32 + HS_T_STRIDE)[j] = s;   // t=1..48
        } else {
            long j = i - R1 - R2 - R3 - R4 - R5;
            uint4 z = { 0u, 0u, 0u, 0u };
            reinterpret_cast<uint4*>(cnt8)[j] = z;
        }
    }
}

// ---------------- GI GEMM: gi = X @ W_ih^T + b_ih (proven gload_lds 128x128) ----------------
__global__ __launch_bounds__(256) void gemm_gi(
    const unsigned short* __restrict__ A, const unsigned short* __restrict__ B,
    const float* __restrict__ bias, float* __restrict__ C, int K, int Ntot, int nM)
{
    const int nwg = gridDim.x;
    const int lin = blockIdx.x;
    const int q = nwg >> 3;
    const int wg = (lin & 7) * q + (lin >> 3);
    const int mi = wg % nM, ni = wg / nM;
    const int m0 = mi * 128, n0 = ni * 128;

    const int tid = threadIdx.x;
    const int lane = tid & 63;
    const int wid = tid >> 6;
    const int wr = wid >> 1, wc = wid & 1;

    __shared__ __align__(16) unsigned short As[128 * 32];
    __shared__ __align__(16) unsigned short Bs[128 * 32];

    f32x4 acc[4][4] = {};
    const int NT = K >> 5;
    const int srow = (lane >> 2);
    const int skk = (lane & 3) * 8;

    for (int kt = 0; kt < NT; ++kt) {
        __syncthreads();
        {
            const int kb = kt * 32;
#pragma unroll
            for (int h2 = 0; h2 < 2; ++h2) {
                const int i = wid + h2 * 4;
                const int row = i * 16 + srow;
                gload_lds16(A + (size_t)(m0 + row) * K + kb + skk, As + i * 512);
                gload_lds16(B + (size_t)(n0 + row) * K + kb + skk, Bs + i * 512);
            }
        }
        __syncthreads();

        const int kg = lane >> 4;
        const int l15 = lane & 15;
        short8 af[4], bf[4];
#pragma unroll
        for (int i = 0; i < 4; ++i) {
            af[i] = *(const short8*)(As + ((wr * 64 + i * 16 + l15) * 32 + kg * 8));
            bf[i] = *(const short8*)(Bs + ((wc * 64 + i * 16 + l15) * 32 + kg * 8));
        }
#pragma unroll
        for (int i = 0; i < 4; ++i)
#pragma unroll
            for (int j = 0; j < 4; ++j)
                acc[i][j] = __builtin_amdgcn_mfma_f32_16x16x32_bf16(af[i], bf[j], acc[i][j], 0, 0, 0);
    }

    const int l15 = lane & 15, lhi = lane >> 4;
#pragma unroll
    for (int i = 0; i < 4; ++i)
#pragma unroll
        for (int j = 0; j < 4; ++j) {
            int col = n0 + wc * 64 + j * 16 + l15;
            float bv = bias[col];
#pragma unroll
            for (int q2 = 0; q2 < 4; ++q2) {
                int row = m0 + wr * 64 + i * 16 + lhi * 4 + q2;
                C[(size_t)row * Ntot + col] = acc[i][j][q2] + bv;
            }
        }
}

// ---------------- FUSED: w_cls convert (workers) + GRU (blocks 0..63) + scores ----------------
// Worker blocks first convert w_cls fp32->bf16 (write-through, overlapped with the
// gru chain), bump wcnt; tile loop gates on wcnt==192. GRU/scores identical to best.
__global__ __launch_bounds__(512, 1) void fused_kernel(
    unsigned int* __restrict__ hs32, unsigned int* __restrict__ hrow32,
    const unsigned short* __restrict__ whh_bf,
    const float* __restrict__ gi, const float* __restrict__ b_hh,
    const float* __restrict__ h0,
    const float* __restrict__ wcls_f, unsigned short* __restrict__ wcls_bf,
    const float* __restrict__ b_cls,
    float* __restrict__ out, unsigned int* __restrict__ cnt8,
    unsigned int* __restrict__ tileq)
{
    __shared__ __align__(16) char smem[124160];             // union: gru Wl+P / worker dbuf
    __shared__ unsigned short Hs[BATCH][JPB];               // 1KB: hnew bounce
    __shared__ int sTile;

    const int tid = threadIdx.x;
    const int bid = blockIdx.x;
    const int lane = tid & 63, wid = tid >> 6;   // 8 waves
    const int l15 = lane & 15, kg = lane >> 4;

    unsigned int* wcnt = cnt8 + 1056;            // own 64B line, zeroed by prep

    if (bid < GRU_BLOCKS) {
        // ================= GRU phase =================
        unsigned short (*Wl)[1032] = reinterpret_cast<unsigned short (*)[1032]>(smem);
        float (*P)[32][49] = reinterpret_cast<float (*)[32][49]>(smem + 99072);

        const int j0 = bid * JPB;
        for (int c = tid; c < 48 * 128; c += 512) {
            int row = c >> 7, k8 = (c & 127) * 8;
            int g = row >> 4, jj = row & 15;
            *(short8*)&Wl[row][k8] =
                *(const short8*)(whh_bf + (size_t)(g * HDIM + j0 + jj) * HDIM + k8);
        }
        const int b = tid >> 4, jj = tid & 15;   // one gate item per thread (512 = 32x16)
        const int gj = j0 + jj;
        const float bhr = b_hh[gj];
        const float bhz = b_hh[HDIM + gj];
        const float bhn = b_hh[2 * HDIM + gj];
        float hloc = h0[b * HDIM + gj];
        __syncthreads();

        for (int t = 0; t < T_STEPS; ++t) {
            const size_t tb = (size_t)t * HS_T_STRIDE;
            const float* gr = gi + (size_t)(t * BATCH + b) * (3 * HDIM);
            float xr = gr[gj], xz = gr[HDIM + gj], xn = gr[2 * HDIM + gj];

            if (tid < 256) {   // 4 MFMA waves
                // per-wave wait: only THIS wave's 2 producer groups
                if (t) {
                    const unsigned int* cp = cnt8 + (size_t)t * CNT_STRIDE + 2 * wid;
                    for (;;) {
                        unsigned ok = (lane < 2)
                            ? (__hip_atomic_load(cp + lane, __ATOMIC_RELAXED, __HIP_MEMORY_SCOPE_AGENT) >= 8u ? 1u : 0u)
                            : 1u;
                        if (__all(ok != 0u)) break;
                        __builtin_amdgcn_s_sleep(2);
                    }
                    asm volatile("" ::: "memory");
                }

                const int kq = wid * 256;
                unsigned wv[8][8];
#pragma unroll
                for (int ks = 0; ks < 8; ++ks) {
                    const int wbase = wid * 128 + ks * 16 + kg * 4;
#pragma unroll
                    for (int mi2 = 0; mi2 < 2; ++mi2) {
                        const int bb = mi2 * 16 + l15;
#pragma unroll
                        for (int q = 0; q < 4; ++q)
                            wv[ks][mi2 * 4 + q] = *(const unsigned*)(
                                hs32 + tb + (size_t)(wbase + q) * 32 + bb);
                    }
                }
                for (;;) {   // sentinel backstop
                    int bad = 0;
#pragma unroll
                    for (int ks = 0; ks < 8; ++ks)
#pragma unroll
                        for (int i = 0; i < 8; ++i)
                            bad |= (wv[ks][i] == SENT);
                    if (!__any(bad)) break;
                    __builtin_amdgcn_s_sleep(1);
#pragma unroll
                    for (int ks = 0; ks < 8; ++ks)
#pragma unroll
                        for (int i = 0; i < 8; ++i)
                            if (wv[ks][i] == SENT) {
                                const int mi2 = i >> 2, q = i & 3;
                                wv[ks][i] = __hip_atomic_load(
                                    hs32 + tb + (size_t)(wid * 128 + ks * 16 + kg * 4 + q) * 32 + (mi2 * 16 + l15),
                                    __ATOMIC_RELAXED, __HIP_MEMORY_SCOPE_AGENT);
                            }
                }
                f32x4 acc[2][3] = {};
#pragma unroll
                for (int ks = 0; ks < 8; ++ks) {
                    const int kb = kq + ks * 32 + kg * 8;
                    union U8 { unsigned u[4]; short8 s; };
                    short8 ah[2];
#pragma unroll
                    for (int mi2 = 0; mi2 < 2; ++mi2) {
                        U8 x;
#pragma unroll
                        for (int q = 0; q < 4; ++q) x.u[q] = wv[ks][mi2 * 4 + q];
                        ah[mi2] = x.s;
                    }
#pragma unroll
                    for (int fr = 0; fr < 3; ++fr) {
                        short8 bh = *(const short8*)&Wl[fr * 16 + l15][kb];
#pragma unroll
                        for (int mi2 = 0; mi2 < 2; ++mi2)
                            acc[mi2][fr] = __builtin_amdgcn_mfma_f32_16x16x32_bf16(ah[mi2], bh, acc[mi2][fr], 0, 0, 0);
                    }
                }
#pragma unroll
                for (int mi2 = 0; mi2 < 2; ++mi2)
#pragma unroll
                    for (int fr = 0; fr < 3; ++fr)
#pragma unroll
                        for (int q = 0; q < 4; ++q)
                            P[wid][mi2 * 16 + kg * 4 + q][fr * 16 + l15] = acc[mi2][fr][q];
            }
            __syncthreads();

            // gates (one item per thread) -> Hs
            {
                float ghr = 0.f, ghz = 0.f, ghn = 0.f;
#pragma unroll
                for (int w = 0; w < 4; ++w) {
                    ghr += P[w][b][jj];
                    ghz += P[w][b][16 + jj];
                    ghn += P[w][b][32 + jj];
                }
                float r = 1.f / (1.f + __expf(-(xr + ghr + bhr)));
                float z = 1.f / (1.f + __expf(-(xz + ghz + bhz)));
                float n = tanhf(xn + r * (ghn + bhn));
                float hnew = (1.f - z) * n + z * hloc;
                hloc = hnew;
                Hs[b][jj] = f2bf(hnew);
            }
            __syncthreads();

            // wide coherent publish: 64 threads hs32, 64 threads hrow32
            if (tid < 64) {
                const int q = tid >> 3, c = tid & 7;
                u32x4 d;
#pragma unroll
                for (int w2 = 0; w2 < 4; ++w2) {
                    int bb = c * 4 + w2;
                    d[w2] = (unsigned)Hs[bb][2 * q] | ((unsigned)Hs[bb][2 * q + 1] << 16);
                }
                store16_coh(hs32 + (size_t)(t + 1) * HS_T_STRIDE + (size_t)((j0 >> 1) + q) * 32 + c * 4, d);
            } else if (tid < 128) {
                const int i = tid - 64, bb = i >> 1, half = i & 1;
                u32x4 d;
#pragma unroll
                for (int w2 = 0; w2 < 4; ++w2) {
                    int q = half * 4 + w2;
                    d[w2] = (unsigned)Hs[bb][2 * q] | ((unsigned)Hs[bb][2 * q + 1] << 16);
                }
                store16_coh(hrow32 + ((size_t)t * BATCH + bb) * 512 + (j0 >> 1) + half * 4, d);
            }
            __syncthreads();   // drains publish stores (vmcnt(0) before s_barrier)
            if (tid == 0)
                __hip_atomic_fetch_add(cnt8 + (size_t)(t + 1) * CNT_STRIDE + (bid >> 3), 1u,
                                       __ATOMIC_RELAXED, __HIP_MEMORY_SCOPE_AGENT);
        }
    } else {
        // ================= w_cls conversion (all 192 worker blocks) =================
        {
            const long UNITS = (long)VOCAB * HDIM / 8;   // 16B bf16 units
            unsigned int* dst = (unsigned int*)wcls_bf;
            for (long u = (long)(bid - GRU_BLOCKS) * 512 + tid; u < UNITS; u += 192L * 512) {
                const float* src = wcls_f + u * 8;
                u32x4 d;
#pragma unroll
                for (int p = 0; p < 4; ++p) {
                    unsigned lo = f2bf(src[2 * p]);
                    unsigned hi = f2bf(src[2 * p + 1]);
                    d[p] = lo | (hi << 16);
                }
                store16_coh(dst + u * 4, d);
            }
            __syncthreads();   // drain conversion stores (vmcnt(0) before s_barrier)
            if (tid == 0)
                __hip_atomic_fetch_add(wcnt, 1u, __ATOMIC_RELAXED, __HIP_MEMORY_SCOPE_AGENT);
        }
        if (bid >= GRU_BLOCKS + EARLY_WORKERS) {
            // ---- throttled workers: stay off the fabric until the recurrence is done ----
            if (wid == 0) {
                const unsigned int* cp = cnt8 + (size_t)T_STEPS * CNT_STRIDE;
                for (;;) {
                    unsigned v = (lane < 8)
                        ? __hip_atomic_load(cp + lane, __ATOMIC_RELAXED, __HIP_MEMORY_SCOPE_AGENT)
                        : 8u;
                    if (__all(v >= 8u)) break;
                    __builtin_amdgcn_s_sleep(64);
                }
            }
            __syncthreads();
        }
    }

    // ---- gate: all of w_cls converted (instant for late arrivals) ----
    if (tid == 0) {
        while (__hip_atomic_load(wcnt, __ATOMIC_RELAXED, __HIP_MEMORY_SCOPE_AGENT) < 192u)
            __builtin_amdgcn_s_sleep(16);
    }
    __syncthreads();
    asm volatile("" ::: "memory");

    // ================= scores worker phase =================
    const unsigned short* hrowA = (const unsigned short*)hrow32;
    const int srow = lane >> 2;
    const int skk = (lane & 3) * 8;

    for (;;) {
        __syncthreads();
        if (tid == 0)
            sTile = (int)__hip_atomic_fetch_add(tileq, 1u, __ATOMIC_RELAXED, __HIP_MEMORY_SCOPE_AGENT);
        __syncthreads();
        const int k = sTile;
        if (k >= N_TILES) break;

        int mi, m0, n0, big;
        if (k < N_BIG) { mi = k / 125; n0 = (k - mi * 125) * 256; m0 = mi * 256; big = 1; }
        else { int idx = k - N_BIG; mi = 5; m0 = 1280 + (idx & 1) * 128; n0 = (idx >> 1) * 256; big = 0; }

        // wait until all h rows for this M-stripe are published
        {
            if (wid == 0) {
                const unsigned int* cp = cnt8 + (size_t)(mi * 8 + 8) * CNT_STRIDE;
                for (;;) {
                    unsigned v = (lane < 8)
                        ? __hip_atomic_load(cp + lane, __ATOMIC_RELAXED, __HIP_MEMORY_SCOPE_AGENT)
                        : 8u;
                    if (__all(v >= 8u)) break;
                    __builtin_amdgcn_s_sleep(32);
                }
            }
            __syncthreads();
            asm volatile("" ::: "memory");
        }

        if (big) {
            // ---- 256x256 tile, 4x2 wave grid (64x128 each), dbuf ----
            const int wm = wid >> 1, wn = wid & 1;
            unsigned short* As0 = (unsigned short*)(smem);
            unsigned short* Bs0 = (unsigned short*)(smem + 16384);
            unsigned short* As1 = (unsigned short*)(smem + 32768);
            unsigned short* Bs1 = (unsigned short*)(smem + 49152);
            f32x4 acc[4][8] = {};

#define STAGE(KT, AB, BB)                                                      \
            {                                                                  \
                const int kb = (KT) * 32;                                      \
                _Pragma("unroll")                                              \
                for (int h2 = 0; h2 < 2; ++h2) {                               \
                    const int i = wid + h2 * 8;                                \
                    const int row = i * 16 + srow;                             \
                    gload_lds16(hrowA + (size_t)(m0 + row) * HDIM + kb + skk, (AB) + i * 512); \
                    gload_lds16(wcls_bf + (size_t)(n0 + row) * HDIM + kb + skk, (BB) + i * 512); \
                }                                                              \
            }
#define COMPUTE(AB, BB)                                                        \
            {                                                                  \
                short8 af[4], bf[8];                                           \
                _Pragma("unroll")                                              \
                for (int i = 0; i < 4; ++i)                                    \
                    af[i] = *(const short8*)((AB) + ((wm * 64 + i * 16 + l15) * 32 + kg * 8)); \
                _Pragma("unroll")                                              \
                for (int j = 0; j < 8; ++j)                                    \
                    bf[j] = *(const short8*)((BB) + ((wn * 128 + j * 16 + l15) * 32 + kg * 8)); \
                _Pragma("unroll")                                              \
                for (int i = 0; i < 4; ++i)                                    \
                    _Pragma("unroll")                                          \
                    for (int j = 0; j < 8; ++j)                                \
                        acc[i][j] = __builtin_amdgcn_mfma_f32_16x16x32_bf16(af[i], bf[j], acc[i][j], 0, 0, 0); \
            }
            STAGE(0, As0, Bs0);
            __syncthreads();
            for (int it = 0; it < 16; ++it) {
                const int kt0 = 2 * it;
                STAGE(kt0 + 1, As1, Bs1);
                COMPUTE(As0, Bs0);
                __syncthreads();
                if (kt0 + 2 < 32) STAGE(kt0 + 2, As0, Bs0);
                COMPUTE(As1, Bs1);
                __syncthreads();
            }
#undef STAGE
#undef COMPUTE
            const int lhi = lane >> 4;
#pragma unroll
            for (int i = 0; i < 4; ++i)
#pragma unroll
                for (int j = 0; j < 8; ++j) {
                    int col = n0 + wn * 128 + j * 16 + l15;
                    float bv = b_cls[col];
#pragma unroll
                    for (int q2 = 0; q2 < 4; ++q2) {
                        int row = m0 + wm * 64 + i * 16 + lhi * 4 + q2;
                        int t = row >> 5, bb = row & 31;
                        __builtin_nontemporal_store(acc[i][j][q2] + bv,
                            &out[(size_t)(bb * T_STEPS + t) * VOCAB + col]);
                    }
                }
        } else {
            // ---- 128x256 tile (tail stripe), 2x4 wave grid (64x64 each), dbuf ----
            const int wm = wid >> 2, wn = wid & 3;
            unsigned short* As0 = (unsigned short*)(smem);            // 8KB
            unsigned short* Bs0 = (unsigned short*)(smem + 8192);     // 16KB
            unsigned short* As1 = (unsigned short*)(smem + 24576);    // 8KB
            unsigned short* Bs1 = (unsigned short*)(smem + 32768);    // 16KB
            f32x4 acc[4][4] = {};

#define STAGE1(KT, AB, BB)                                                     \
            {                                                                  \
                const int kb = (KT) * 32;                                      \
                _Pragma("unroll")                                              \
                for (int h2 = 0; h2 < 3; ++h2) {                               \
                    const int c = wid * 3 + h2;       /* 0..23 */              \
                    if (c < 8) {                                               \
                        const int row = c * 16 + srow;                         \
                        gload_lds16(hrowA + (size_t)(m0 + row) * HDIM + kb + skk, (AB) + c * 512); \
                    } else {                                                   \
                        const int row = (c - 8) * 16 + srow;                   \
                        gload_lds16(wcls_bf + (size_t)(n0 + row) * HDIM + kb + skk, (BB) + (c - 8) * 512); \
                    }                                                          \
                }                                                              \
            }
#define COMPUTE1(AB, BB)                                                       \
            {                                                                  \
                short8 af[4], bf[4];                                           \
                _Pragma("unroll")                                              \
                for (int i = 0; i < 4; ++i)                                    \
                    af[i] = *(const short8*)((AB) + ((wm * 64 + i * 16 + l15) * 32 + kg * 8)); \
                _Pragma("unroll")                                              \
                for (int j = 0; j < 4; ++j)                                    \
                    bf[j] = *(const short8*)((BB) + ((wn * 64 + j * 16 + l15) * 32 + kg * 8)); \
                _Pragma("unroll")                                              \
                for (int i = 0; i < 4; ++i)                                    \
                    _Pragma("unroll")                                          \
                    for (int j = 0; j < 4; ++j)                                \
                        acc[i][j] = __builtin_amdgcn_mfma_f32_16x16x32_bf16(af[i], bf[j], acc[i][j], 0, 0, 0); \
            }
            STAGE1(0, As0, Bs0);
            __syncthreads();
            for (int it = 0; it < 16; ++it) {
                const int kt0 = 2 * it;
                STAGE1(kt0 + 1, As1, Bs1);
                COMPUTE1(As0, Bs0);
                __syncthreads();
                if (kt0 + 2 < 32) STAGE1(kt0 + 2, As0, Bs0);
                COMPUTE1(As1, Bs1);
                __syncthreads();
            }
#undef STAGE1
#undef COMPUTE1
            const int lhi = lane >> 4;
#pragma unroll
            for (int i = 0; i < 4; ++i)
#pragma unroll
                for (int j = 0; j < 4; ++j) {
                    int col = n0 + wn * 64 + j * 16 + l15;
                    float bv = b_cls[col];
#pragma unroll
                    for (int q2 = 0; q2 < 4; ++q2) {
                        int row = m0 + wm * 64 + i * 16 + lhi * 4 + q2;
                        int t = row >> 5, bb = row & 31;
                        __builtin_nontemporal_store(acc[i][j][q2] + bv,
                            &out[(size_t)(bb * T_STEPS + t) * VOCAB + col]);
                    }
                }
        }
    }
}

extern "C" void kernel_launch(void* const* d_in, const int* in_sizes, int n_in,
                              void* d_out, int out_size, void* d_ws, size_t ws_size,
                              hipStream_t stream) {
    const float* h0    = (const float*)d_in[0];
    const int*   tseq  = (const int*)d_in[1];
    const float* emb   = (const float*)d_in[2];
    const float* w_ih  = (const float*)d_in[3];
    const float* w_hh  = (const float*)d_in[4];
    const float* b_ih  = (const float*)d_in[5];
    const float* b_hh  = (const float*)d_in[6];
    const float* w_cls = (const float*)d_in[7];
    const float* b_cls = (const float*)d_in[8];
    float* out = (float*)d_out;

    char* w = (char*)d_ws;
    unsigned short* wcls_bf = (unsigned short*)w; w += (size_t)VOCAB * HDIM * 2;
    unsigned short* wih_bf  = (unsigned short*)w; w += (size_t)3 * HDIM * EDIM * 2;
    unsigned short* whh_bf  = (unsigned short*)w; w += (size_t)3 * HDIM * HDIM * 2;
    unsigned short* x_bf    = (unsigned short*)w; w += (size_t)T_STEPS * BATCH * EDIM * 2;
    unsigned int*   hs32    = (unsigned int*)w;   w += (size_t)(T_STEPS + 1) * HS_T_STRIDE * 4;
    unsigned int*   hrow32  = (unsigned int*)w;   w += (size_t)T_STEPS * BATCH * 512 * 4;
    float* gi               = (float*)w;          w += (size_t)T_STEPS * BATCH * 3 * HDIM * 4;
    unsigned int* cnt8      = (unsigned int*)w;   w += 8192;
    unsigned int* tileq     = cnt8 + 1024;        // own 64B line, zeroed with cnt8

    prep_kernel<<<2048, 256, 0, stream>>>(h0, tseq, emb, w_ih, w_hh,
                                          wih_bf, whh_bf, x_bf, hs32, cnt8);

    // GI = X @ W_ih^T + b_ih : M=1536, N=3072, K=512  (288 wgs, %8==0)
    gemm_gi<<<(T_STEPS * BATCH / 128) * (3 * HDIM / 128), 256, 0, stream>>>(
        x_bf, wih_bf, b_ih, gi, EDIM, 3 * HDIM, T_STEPS * BATCH / 128);

    // fused w_cls-convert + GRU + overlapped scores: 256 blocks (1/CU, co-resident)
    fused_kernel<<<256, 512, 0, stream>>>(hs32, hrow32, whh_bf, gi, b_hh, h0,
                                          w_cls, wcls_bf, b_cls, out, cnt8, tileq);
}

// Round 24
// 324.359 us; speedup vs baseline: 1.3246x; 1.0199x over previous
//
#include <hip/hip_runtime.h>
#include <hip/hip_bf16.h>

typedef __attribute__((ext_vector_type(8))) short short8;
typedef __attribute__((ext_vector_type(4))) float f32x4;
typedef __attribute__((ext_vector_type(4))) unsigned int u32x4;

#define T_STEPS 48
#define BATCH 32
#define EDIM 512
#define HDIM 1024
#define VOCAB 32000
#define GRU_BLOCKS 64
#define JPB 16
#define SENT 0x7FFF7FFFu
#define N_BIG 625                  // stripes 0..4: 256x256 tiles (5 x 125)
#define N_TILES 875                // + stripe 5 as 250 tiles of 128x256
#define GI_TILES 288               // GI: 12 M-stripes x 24 N-tiles (128x128)
#define CNT_STRIDE 16              // uints per counter slot (64B padded)
#define EARLY_WORKERS 96           // blocks 64..159 work during gru; 160+ throttled

// packed h storage (hi-plane only): uint words, [t(49)][k_pair(512)][b(32)]
#define HS_T_STRIDE 16384          // uints per t-slot

__device__ __forceinline__ unsigned short f2bf(float f) {
    __hip_bfloat16 h = __float2bfloat16(f);
    return *reinterpret_cast<unsigned short*>(&h);
}
__device__ __forceinline__ float bf2f(unsigned short u) {
    union { unsigned int i; float f; } v;
    v.i = ((unsigned int)u) << 16;
    return v.f;
}
__device__ __forceinline__ void astoref(float* p, float v) {
    union { float f; unsigned u; } c; c.f = v;
    __hip_atomic_store((unsigned*)p, c.u, __ATOMIC_RELAXED, __HIP_MEMORY_SCOPE_AGENT);
}

typedef __attribute__((address_space(1))) const void GAS;
typedef __attribute__((address_space(3))) void LAS;
__device__ __forceinline__ void gload_lds16(const unsigned short* g, unsigned short* l) {
    __builtin_amdgcn_global_load_lds((GAS*)g, (LAS*)(unsigned)(uintptr_t)l, 16, 0, 0);
}

// coherent (cross-XCD visible) 16B store
__device__ __forceinline__ void store16_coh(unsigned int* p, u32x4 v) {
    asm volatile("global_store_dwordx4 %0, %1, off sc0 sc1"
                 :: "v"((unsigned long long)(uintptr_t)p), "v"(v) : "memory");
}

// counter layout within cnt8 (2048 uints, zeroed by prep):
//   step counters:  cnt8 + t*CNT_STRIDE (t=1..48, 8 producer-group sub-counters)
//   tileq:          cnt8 + 1024
//   giTileq:        cnt8 + 1040
//   wcnt:           cnt8 + 1056
//   giq[stripe]:    cnt8 + 1280 + stripe*CNT_STRIDE (stripe 0..11, counts to 24)

// ---------------- prep: small conversions, gather, h0 pack, sentinel fill, cnt zero ----------------
__global__ __launch_bounds__(256) void prep_kernel(
    const float* __restrict__ h0, const int* __restrict__ tseq,
    const float* __restrict__ emb, const float* __restrict__ w_ih,
    const float* __restrict__ w_hh,
    unsigned short* __restrict__ wih_bf, unsigned short* __restrict__ whh_bf,
    unsigned short* __restrict__ x_bf,
    unsigned int* __restrict__ hs32, unsigned int* __restrict__ cnt8)
{
    const long R1 = (long)3 * HDIM * EDIM / 4;        // w_ih
    const long R2 = (long)3 * HDIM * HDIM / 4;        // w_hh (hi only)
    const long R3 = (long)T_STEPS * BATCH * EDIM / 4; // X gather
    const long R4 = (long)HS_T_STRIDE;                // h0 -> packed slot 0
    const long R5 = (long)T_STEPS * HS_T_STRIDE / 4;  // sentinel fill t=1..48 (uint4)
    const long R6 = 512;                              // counters zero: 2048 uints
    const long total = R1 + R2 + R3 + R4 + R5 + R6;

    for (long i = (long)blockIdx.x * blockDim.x + threadIdx.x; i < total;
         i += (long)gridDim.x * blockDim.x) {
        if (i < R1) {
            long j = i;
            float4 v = reinterpret_cast<const float4*>(w_ih)[j];
            ushort4 u = { f2bf(v.x), f2bf(v.y), f2bf(v.z), f2bf(v.w) };
            *reinterpret_cast<ushort4*>(wih_bf + j * 4) = u;
        } else if (i < R1 + R2) {
            long j = i - R1;
            float4 v = reinterpret_cast<const float4*>(w_hh)[j];
            ushort4 u = { f2bf(v.x), f2bf(v.y), f2bf(v.z), f2bf(v.w) };
            *reinterpret_cast<ushort4*>(whh_bf + j * 4) = u;
        } else if (i < R1 + R2 + R3) {
            long j = i - R1 - R2;
            int m = (int)(j >> 7);
            int kk4 = (int)(j & 127);
            int t = m >> 5, b = m & 31;
            int tok = tseq[b * T_STEPS + t];
            float4 v = reinterpret_cast<const float4*>(emb)[(long)tok * (EDIM / 4) + kk4];
            ushort4 u = { f2bf(v.x), f2bf(v.y), f2bf(v.z), f2bf(v.w) };
            *reinterpret_cast<ushort4*>(x_bf + (long)m * EDIM + kk4 * 4) = u;
        } else if (i < R1 + R2 + R3 + R4) {
            long j = i - R1 - R2 - R3;            // uint index: w*32 + b
            int w = (int)(j >> 5), b = (int)(j & 31);
            unsigned short a = f2bf(h0[b * HDIM + 2 * w]);
            unsigned short c = f2bf(h0[b * HDIM + 2 * w + 1]);
            hs32[j] = (unsigned)a | ((unsigned)c << 16);
        } else if (i < R1 + R2 + R3 + R4 + R5) {
            long j = i - R1 - R2 - R3 - R4;
            uint4 s = { SENT, SENT, SENT, SENT };
            reinterpret_cast<uint4*>(hs32 + HS_T_STRIDE)[j] = s;   // t=1..48
        } else {
            long j = i - R1 - R2 - R3 - R4 - R5;
            uint4 z = { 0u, 0u, 0u, 0u };
            reinterpret_cast<uint4*>(cnt8)[j] = z;
        }
    }
}

// ---------------- FUSED: GI + w_cls convert (workers) + GRU + scores ----------------
// Workers: GI tiles first (write-through gi + per-stripe counters), then w_cls
// conversion, then scores tiles. GRU consumes gi via NORMAL cached loads —
// safe because every gi address is first-touched only after its stripe counter
// was verified (pre-loop stripe-0 wait + one-step-ahead stripe check).
__global__ __launch_bounds__(512, 1) void fused_kernel(
    unsigned int* __restrict__ hs32, unsigned int* __restrict__ hrow32,
    const unsigned short* __restrict__ whh_bf,
    float* __restrict__ gi, const float* __restrict__ b_hh,
    const float* __restrict__ h0,
    const float* __restrict__ wcls_f, unsigned short* __restrict__ wcls_bf,
    const float* __restrict__ b_cls,
    const unsigned short* __restrict__ x_bf, const unsigned short* __restrict__ wih_bf,
    const float* __restrict__ b_ih,
    float* __restrict__ out, unsigned int* __restrict__ cnt8)
{
    __shared__ __align__(16) char smem[124160];             // union: gru Wl+P / worker bufs
    __shared__ unsigned short Hs[BATCH][JPB];               // 1KB: hnew bounce
    __shared__ int sTile;

    const int tid = threadIdx.x;
    const int bid = blockIdx.x;
    const int lane = tid & 63, wid = tid >> 6;   // 8 waves
    const int l15 = lane & 15, kg = lane >> 4;

    unsigned int* tileq   = cnt8 + 1024;
    unsigned int* giTileq = cnt8 + 1040;
    unsigned int* wcnt    = cnt8 + 1056;

    if (bid < GRU_BLOCKS) {
        // ================= GRU phase =================
        unsigned short (*Wl)[1032] = reinterpret_cast<unsigned short (*)[1032]>(smem);
        float (*P)[32][49] = reinterpret_cast<float (*)[32][49]>(smem + 99072);

        const int j0 = bid * JPB;
        for (int c = tid; c < 48 * 128; c += 512) {
            int row = c >> 7, k8 = (c & 127) * 8;
            int g = row >> 4, jj = row & 15;
            *(short8*)&Wl[row][k8] =
                *(const short8*)(whh_bf + (size_t)(g * HDIM + j0 + jj) * HDIM + k8);
        }
        const int b = tid >> 4, jj = tid & 15;   // one gate item per thread (512 = 32x16)
        const int gj = j0 + jj;
        const float bhr = b_hh[gj];
        const float bhz = b_hh[HDIM + gj];
        const float bhn = b_hh[2 * HDIM + gj];
        float hloc = h0[b * HDIM + gj];
        // pre-loop: wait for gi stripe 0 (covers top-loads of steps 0..3)
        if (tid == 0) {
            while (__hip_atomic_load(cnt8 + 1280, __ATOMIC_RELAXED, __HIP_MEMORY_SCOPE_AGENT) < 24u)
                __builtin_amdgcn_s_sleep(8);
        }
        __syncthreads();
        asm volatile("" ::: "memory");

        for (int t = 0; t < T_STEPS; ++t) {
            const size_t tb = (size_t)t * HS_T_STRIDE;
            // speculative gi top-load: stripe t>>2 verified in a previous iteration
            const float* gr = gi + (size_t)(t * BATCH + b) * (3 * HDIM);
            float xr = gr[gj], xz = gr[HDIM + gj], xn = gr[2 * HDIM + gj];

            if (tid < 256) {   // 4 MFMA waves
                // per-wave wait: this wave's 2 producer groups + NEXT step's gi stripe
                if (t) {
                    const unsigned int* cp = cnt8 + (size_t)t * CNT_STRIDE + 2 * wid;
                    const int s1 = ((t + 1) >> 2) < 12 ? ((t + 1) >> 2) : 11;
                    const unsigned int* gq = cnt8 + 1280 + (size_t)s1 * CNT_STRIDE;
                    for (;;) {
                        unsigned ok;
                        if (lane < 2)
                            ok = (__hip_atomic_load(cp + lane, __ATOMIC_RELAXED, __HIP_MEMORY_SCOPE_AGENT) >= 8u) ? 1u : 0u;
                        else if (lane == 2)
                            ok = (__hip_atomic_load(gq, __ATOMIC_RELAXED, __HIP_MEMORY_SCOPE_AGENT) >= 24u) ? 1u : 0u;
                        else
                            ok = 1u;
                        if (__all(ok != 0u)) break;
                        __builtin_amdgcn_s_sleep(2);
                    }
                    asm volatile("" ::: "memory");
                }

                const int kq = wid * 256;
                unsigned wv[8][8];
#pragma unroll
                for (int ks = 0; ks < 8; ++ks) {
                    const int wbase = wid * 128 + ks * 16 + kg * 4;
#pragma unroll
                    for (int mi2 = 0; mi2 < 2; ++mi2) {
                        const int bb = mi2 * 16 + l15;
#pragma unroll
                        for (int q = 0; q < 4; ++q)
                            wv[ks][mi2 * 4 + q] = *(const unsigned*)(
                                hs32 + tb + (size_t)(wbase + q) * 32 + bb);
                    }
                }
                for (;;) {   // sentinel backstop
                    int bad = 0;
#pragma unroll
                    for (int ks = 0; ks < 8; ++ks)
#pragma unroll
                        for (int i = 0; i < 8; ++i)
                            bad |= (wv[ks][i] == SENT);
                    if (!__any(bad)) break;
                    __builtin_amdgcn_s_sleep(1);
#pragma unroll
                    for (int ks = 0; ks < 8; ++ks)
#pragma unroll
                        for (int i = 0; i < 8; ++i)
                            if (wv[ks][i] == SENT) {
                                const int mi2 = i >> 2, q = i & 3;
                                wv[ks][i] = __hip_atomic_load(
                                    hs32 + tb + (size_t)(wid * 128 + ks * 16 + kg * 4 + q) * 32 + (mi2 * 16 + l15),
                                    __ATOMIC_RELAXED, __HIP_MEMORY_SCOPE_AGENT);
                            }
                }
                f32x4 acc[2][3] = {};
#pragma unroll
                for (int ks = 0; ks < 8; ++ks) {
                    const int kb = kq + ks * 32 + kg * 8;
                    union U8 { unsigned u[4]; short8 s; };
                    short8 ah[2];
#pragma unroll
                    for (int mi2 = 0; mi2 < 2; ++mi2) {
                        U8 x;
#pragma unroll
                        for (int q = 0; q < 4; ++q) x.u[q] = wv[ks][mi2 * 4 + q];
                        ah[mi2] = x.s;
                    }
#pragma unroll
                    for (int fr = 0; fr < 3; ++fr) {
                        short8 bh = *(const short8*)&Wl[fr * 16 + l15][kb];
#pragma unroll
                        for (int mi2 = 0; mi2 < 2; ++mi2)
                            acc[mi2][fr] = __builtin_amdgcn_mfma_f32_16x16x32_bf16(ah[mi2], bh, acc[mi2][fr], 0, 0, 0);
                    }
                }
#pragma unroll
                for (int mi2 = 0; mi2 < 2; ++mi2)
#pragma unroll
                    for (int fr = 0; fr < 3; ++fr)
#pragma unroll
                        for (int q = 0; q < 4; ++q)
                            P[wid][mi2 * 16 + kg * 4 + q][fr * 16 + l15] = acc[mi2][fr][q];
            }
            __syncthreads();

            // gates (one item per thread) -> Hs
            {
                float ghr = 0.f, ghz = 0.f, ghn = 0.f;
#pragma unroll
                for (int w = 0; w < 4; ++w) {
                    ghr += P[w][b][jj];
                    ghz += P[w][b][16 + jj];
                    ghn += P[w][b][32 + jj];
                }
                float r = 1.f / (1.f + __expf(-(xr + ghr + bhr)));
                float z = 1.f / (1.f + __expf(-(xz + ghz + bhz)));
                float n = tanhf(xn + r * (ghn + bhn));
                float hnew = (1.f - z) * n + z * hloc;
                hloc = hnew;
                Hs[b][jj] = f2bf(hnew);
            }
            __syncthreads();

            // wide coherent publish: 64 threads hs32, 64 threads hrow32
            if (tid < 64) {
                const int q = tid >> 3, c = tid & 7;
                u32x4 d;
#pragma unroll
                for (int w2 = 0; w2 < 4; ++w2) {
                    int bb = c * 4 + w2;
                    d[w2] = (unsigned)Hs[bb][2 * q] | ((unsigned)Hs[bb][2 * q + 1] << 16);
                }
                store16_coh(hs32 + (size_t)(t + 1) * HS_T_STRIDE + (size_t)((j0 >> 1) + q) * 32 + c * 4, d);
            } else if (tid < 128) {
                const int i = tid - 64, bb = i >> 1, half = i & 1;
                u32x4 d;
#pragma unroll
                for (int w2 = 0; w2 < 4; ++w2) {
                    int q = half * 4 + w2;
                    d[w2] = (unsigned)Hs[bb][2 * q] | ((unsigned)Hs[bb][2 * q + 1] << 16);
                }
                store16_coh(hrow32 + ((size_t)t * BATCH + bb) * 512 + (j0 >> 1) + half * 4, d);
            }
            __syncthreads();   // drains publish stores (vmcnt(0) before s_barrier)
            if (tid == 0)
                __hip_atomic_fetch_add(cnt8 + (size_t)(t + 1) * CNT_STRIDE + (bid >> 3), 1u,
                                       __ATOMIC_RELAXED, __HIP_MEMORY_SCOPE_AGENT);
        }
    } else {
        // ================= GI phase (all 192 workers): gi = X @ W_ih^T + b_ih ==========
        {
            unsigned short* As0 = (unsigned short*)(smem);
            unsigned short* Bs0 = (unsigned short*)(smem + 8192);
            const int srow = lane >> 2, skk = (lane & 3) * 8;
            const int wr2 = wid >> 2, wc2 = wid & 3;   // 2x4 wave grid: 64x32 each
            const int lhi = lane >> 4;

            for (;;) {
                __syncthreads();
                if (tid == 0)
                    sTile = (int)__hip_atomic_fetch_add(giTileq, 1u, __ATOMIC_RELAXED, __HIP_MEMORY_SCOPE_AGENT);
                __syncthreads();
                const int k = sTile;
                if (k >= GI_TILES) break;
                const int mi = k / 24, ni = k - mi * 24;   // mi-major: stripe 0 first
                const int m0 = mi * 128, n0 = ni * 128;

                f32x4 acc[4][2] = {};
                for (int kt = 0; kt < 16; ++kt) {
                    __syncthreads();
                    {
                        const int kb = kt * 32;
                        const int row = wid * 16 + srow;
                        gload_lds16(x_bf + (size_t)(m0 + row) * EDIM + kb + skk, As0 + wid * 512);
                        gload_lds16(wih_bf + (size_t)(n0 + row) * EDIM + kb + skk, Bs0 + wid * 512);
                    }
                    __syncthreads();
                    short8 af[4], bfr[2];
#pragma unroll
                    for (int i = 0; i < 4; ++i)
                        af[i] = *(const short8*)(As0 + ((wr2 * 64 + i * 16 + l15) * 32 + kg * 8));
#pragma unroll
                    for (int j = 0; j < 2; ++j)
                        bfr[j] = *(const short8*)(Bs0 + ((wc2 * 32 + j * 16 + l15) * 32 + kg * 8));
#pragma unroll
                    for (int i = 0; i < 4; ++i)
#pragma unroll
                        for (int j = 0; j < 2; ++j)
                            acc[i][j] = __builtin_amdgcn_mfma_f32_16x16x32_bf16(af[i], bfr[j], acc[i][j], 0, 0, 0);
                }
                // coherent epilogue (cross-XCD consumers within this kernel)
#pragma unroll
                for (int i = 0; i < 4; ++i)
#pragma unroll
                    for (int j = 0; j < 2; ++j) {
                        int col = n0 + wc2 * 32 + j * 16 + l15;
                        float bv = b_ih[col];
#pragma unroll
                        for (int q2 = 0; q2 < 4; ++q2) {
                            int row = m0 + wr2 * 64 + i * 16 + lhi * 4 + q2;
                            astoref(&gi[(size_t)row * (3 * HDIM) + col], acc[i][j][q2] + bv);
                        }
                    }
                __syncthreads();   // drain gi stores (vmcnt(0) before s_barrier)
                if (tid == 0)
                    __hip_atomic_fetch_add(cnt8 + 1280 + (size_t)mi * CNT_STRIDE, 1u,
                                           __ATOMIC_RELAXED, __HIP_MEMORY_SCOPE_AGENT);
            }
        }
        // ================= w_cls conversion (all 192 workers) =================
        {
            const long UNITS = (long)VOCAB * HDIM / 8;   // 16B bf16 units
            unsigned int* dst = (unsigned int*)wcls_bf;
            for (long u = (long)(bid - GRU_BLOCKS) * 512 + tid; u < UNITS; u += 192L * 512) {
                const float* src = wcls_f + u * 8;
                u32x4 d;
#pragma unroll
                for (int p = 0; p < 4; ++p) {
                    unsigned lo = f2bf(src[2 * p]);
                    unsigned hi = f2bf(src[2 * p + 1]);
                    d[p] = lo | (hi << 16);
                }
                store16_coh(dst + u * 4, d);
            }
            __syncthreads();   // drain conversion stores
            if (tid == 0)
                __hip_atomic_fetch_add(wcnt, 1u, __ATOMIC_RELAXED, __HIP_MEMORY_SCOPE_AGENT);
        }
        if (bid >= GRU_BLOCKS + EARLY_WORKERS) {
            // ---- throttled workers: stay off the fabric until the recurrence is done ----
            if (wid == 0) {
                const unsigned int* cp = cnt8 + (size_t)T_STEPS * CNT_STRIDE;
                for (;;) {
                    unsigned v = (lane < 8)
                        ? __hip_atomic_load(cp + lane, __ATOMIC_RELAXED, __HIP_MEMORY_SCOPE_AGENT)
                        : 8u;
                    if (__all(v >= 8u)) break;
                    __builtin_amdgcn_s_sleep(64);
                }
            }
            __syncthreads();
        }
    }

    // ---- gate: all of w_cls converted (instant for late arrivals) ----
    if (tid == 0) {
        while (__hip_atomic_load(wcnt, __ATOMIC_RELAXED, __HIP_MEMORY_SCOPE_AGENT) < 192u)
            __builtin_amdgcn_s_sleep(16);
    }
    __syncthreads();
    asm volatile("" ::: "memory");

    // ================= scores worker phase =================
    const unsigned short* hrowA = (const unsigned short*)hrow32;
    const int srow = lane >> 2;
    const int skk = (lane & 3) * 8;

    for (;;) {
        __syncthreads();
        if (tid == 0)
            sTile = (int)__hip_atomic_fetch_add(tileq, 1u, __ATOMIC_RELAXED, __HIP_MEMORY_SCOPE_AGENT);
        __syncthreads();
        const int k = sTile;
        if (k >= N_TILES) break;

        int mi, m0, n0, big;
        if (k < N_BIG) { mi = k / 125; n0 = (k - mi * 125) * 256; m0 = mi * 256; big = 1; }
        else { int idx = k - N_BIG; mi = 5; m0 = 1280 + (idx & 1) * 128; n0 = (idx >> 1) * 256; big = 0; }

        // wait until all h rows for this M-stripe are published
        {
            if (wid == 0) {
                const unsigned int* cp = cnt8 + (size_t)(mi * 8 + 8) * CNT_STRIDE;
                for (;;) {
                    unsigned v = (lane < 8)
                        ? __hip_atomic_load(cp + lane, __ATOMIC_RELAXED, __HIP_MEMORY_SCOPE_AGENT)
                        : 8u;
                    if (__all(v >= 8u)) break;
                    __builtin_amdgcn_s_sleep(32);
                }
            }
            __syncthreads();
            asm volatile("" ::: "memory");
        }

        if (big) {
            // ---- 256x256 tile, 4x2 wave grid (64x128 each), dbuf ----
            const int wm = wid >> 1, wn = wid & 1;
            unsigned short* As0 = (unsigned short*)(smem);
            unsigned short* Bs0 = (unsigned short*)(smem + 16384);
            unsigned short* As1 = (unsigned short*)(smem + 32768);
            unsigned short* Bs1 = (unsigned short*)(smem + 49152);
            f32x4 acc[4][8] = {};

#define STAGE(KT, AB, BB)                                                      \
            {                                                                  \
                const int kb = (KT) * 32;                                      \
                _Pragma("unroll")                                              \
                for (int h2 = 0; h2 < 2; ++h2) {                               \
                    const int i = wid + h2 * 8;                                \
                    const int row = i * 16 + srow;                             \
                    gload_lds16(hrowA + (size_t)(m0 + row) * HDIM + kb + skk, (AB) + i * 512); \
                    gload_lds16(wcls_bf + (size_t)(n0 + row) * HDIM + kb + skk, (BB) + i * 512); \
                }                                                              \
            }
#define COMPUTE(AB, BB)                                                        \
            {                                                                  \
                short8 af[4], bf[8];                                           \
                _Pragma("unroll")                                              \
                for (int i = 0; i < 4; ++i)                                    \
                    af[i] = *(const short8*)((AB) + ((wm * 64 + i * 16 + l15) * 32 + kg * 8)); \
                _Pragma("unroll")                                              \
                for (int j = 0; j < 8; ++j)                                    \
                    bf[j] = *(const short8*)((BB) + ((wn * 128 + j * 16 + l15) * 32 + kg * 8)); \
                _Pragma("unroll")                                              \
                for (int i = 0; i < 4; ++i)                                    \
                    _Pragma("unroll")                                          \
                    for (int j = 0; j < 8; ++j)                                \
                        acc[i][j] = __builtin_amdgcn_mfma_f32_16x16x32_bf16(af[i], bf[j], acc[i][j], 0, 0, 0); \
            }
            STAGE(0, As0, Bs0);
            __syncthreads();
            for (int it = 0; it < 16; ++it) {
                const int kt0 = 2 * it;
                STAGE(kt0 + 1, As1, Bs1);
                COMPUTE(As0, Bs0);
                __syncthreads();
                if (kt0 + 2 < 32) STAGE(kt0 + 2, As0, Bs0);
                COMPUTE(As1, Bs1);
                __syncthreads();
            }
#undef STAGE
#undef COMPUTE
            const int lhi = lane >> 4;
#pragma unroll
            for (int i = 0; i < 4; ++i)
#pragma unroll
                for (int j = 0; j < 8; ++j) {
                    int col = n0 + wn * 128 + j * 16 + l15;
                    float bv = b_cls[col];
#pragma unroll
                    for (int q2 = 0; q2 < 4; ++q2) {
                        int row = m0 + wm * 64 + i * 16 + lhi * 4 + q2;
                        int t = row >> 5, bb = row & 31;
                        __builtin_nontemporal_store(acc[i][j][q2] + bv,
                            &out[(size_t)(bb * T_STEPS + t) * VOCAB + col]);
                    }
                }
        } else {
            // ---- 128x256 tile (tail stripe), 2x4 wave grid (64x64 each), dbuf ----
            const int wm = wid >> 2, wn = wid & 3;
            unsigned short* As0 = (unsigned short*)(smem);            // 8KB
            unsigned short* Bs0 = (unsigned short*)(smem + 8192);     // 16KB
            unsigned short* As1 = (unsigned short*)(smem + 24576);    // 8KB
            unsigned short* Bs1 = (unsigned short*)(smem + 32768);    // 16KB
            f32x4 acc[4][4] = {};

#define STAGE1(KT, AB, BB)                                                     \
            {                                                                  \
                const int kb = (KT) * 32;                                      \
                _Pragma("unroll")                                              \
                for (int h2 = 0; h2 < 3; ++h2) {                               \
                    const int c = wid * 3 + h2;       /* 0..23 */              \
                    if (c < 8) {                                               \
                        const int row = c * 16 + srow;                         \
                        gload_lds16(hrowA + (size_t)(m0 + row) * HDIM + kb + skk, (AB) + c * 512); \
                    } else {                                                   \
                        const int row = (c - 8) * 16 + srow;                   \
                        gload_lds16(wcls_bf + (size_t)(n0 + row) * HDIM + kb + skk, (BB) + (c - 8) * 512); \
                    }                                                          \
                }                                                              \
            }
#define COMPUTE1(AB, BB)                                                       \
            {                                                                  \
                short8 af[4], bf[4];                                           \
                _Pragma("unroll")                                              \
                for (int i = 0; i < 4; ++i)                                    \
                    af[i] = *(const short8*)((AB) + ((wm * 64 + i * 16 + l15) * 32 + kg * 8)); \
                _Pragma("unroll")                                              \
                for (int j = 0; j < 4; ++j)                                    \
                    bf[j] = *(const short8*)((BB) + ((wn * 64 + j * 16 + l15) * 32 + kg * 8)); \
                _Pragma("unroll")                                              \
                for (int i = 0; i < 4; ++i)                                    \
                    _Pragma("unroll")                                          \
                    for (int j = 0; j < 4; ++j)                                \
                        acc[i][j] = __builtin_amdgcn_mfma_f32_16x16x32_bf16(af[i], bf[j], acc[i][j], 0, 0, 0); \
            }
            STAGE1(0, As0, Bs0);
            __syncthreads();
            for (int it = 0; it < 16; ++it) {
                const int kt0 = 2 * it;
                STAGE1(kt0 + 1, As1, Bs1);
                COMPUTE1(As0, Bs0);
                __syncthreads();
                if (kt0 + 2 < 32) STAGE1(kt0 + 2, As0, Bs0);
                COMPUTE1(As1, Bs1);
                __syncthreads();
            }
#undef STAGE1
#undef COMPUTE1
            const int lhi = lane >> 4;
#pragma unroll
            for (int i = 0; i < 4; ++i)
#pragma unroll
                for (int j = 0; j < 4; ++j) {
                    int col = n0 + wn * 64 + j * 16 + l15;
                    float bv = b_cls[col];
#pragma unroll
                    for (int q2 = 0; q2 < 4; ++q2) {
                        int row = m0 + wm * 64 + i * 16 + lhi * 4 + q2;
                        int t = row >> 5, bb = row & 31;
                        __builtin_nontemporal_store(acc[i][j][q2] + bv,
                            &out[(size_t)(bb * T_STEPS + t) * VOCAB + col]);
                    }
                }
        }
    }
}

extern "C" void kernel_launch(void* const* d_in, const int* in_sizes, int n_in,
                              void* d_out, int out_size, void* d_ws, size_t ws_size,
                              hipStream_t stream) {
    const float* h0    = (const float*)d_in[0];
    const int*   tseq  = (const int*)d_in[1];
    const float* emb   = (const float*)d_in[2];
    const float* w_ih  = (const float*)d_in[3];
    const float* w_hh  = (const float*)d_in[4];
    const float* b_ih  = (const float*)d_in[5];
    const float* b_hh  = (const float*)d_in[6];
    const float* w_cls = (const float*)d_in[7];
    const float* b_cls = (const float*)d_in[8];
    float* out = (float*)d_out;

    char* w = (char*)d_ws;
    unsigned short* wcls_bf = (unsigned short*)w; w += (size_t)VOCAB * HDIM * 2;
    unsigned short* wih_bf  = (unsigned short*)w; w += (size_t)3 * HDIM * EDIM * 2;
    unsigned short* whh_bf  = (unsigned short*)w; w += (size_t)3 * HDIM * HDIM * 2;
    unsigned short* x_bf    = (unsigned short*)w; w += (size_t)T_STEPS * BATCH * EDIM * 2;
    unsigned int*   hs32    = (unsigned int*)w;   w += (size_t)(T_STEPS + 1) * HS_T_STRIDE * 4;
    unsigned int*   hrow32  = (unsigned int*)w;   w += (size_t)T_STEPS * BATCH * 512 * 4;
    float* gi               = (float*)w;          w += (size_t)T_STEPS * BATCH * 3 * HDIM * 4;
    unsigned int* cnt8      = (unsigned int*)w;   w += 8192;

    prep_kernel<<<2048, 256, 0, stream>>>(h0, tseq, emb, w_ih, w_hh,
                                          wih_bf, whh_bf, x_bf, hs32, cnt8);

    // fused GI + w_cls-convert + GRU + overlapped scores: 256 blocks (1/CU)
    fused_kernel<<<256, 512, 0, stream>>>(hs32, hrow32, whh_bf, gi, b_hh, h0,
                                          w_cls, wcls_bf, b_cls,
                                          x_bf, wih_bf, b_ih, out, cnt8);
}